// Round 11
// baseline (702.150 us; speedup 1.0000x reference)
//
#include <hip/hip_runtime.h>
#include <hip/hip_bf16.h>

#define MAXD 32
typedef __hip_bfloat16 bf16;

__device__ __forceinline__ float bf2f(bf16 v) { return __bfloat162float(v); }
__device__ __forceinline__ float2 ldbf2(const bf16* p) {
  unsigned u = *(const unsigned*)p;
  return make_float2(__uint_as_float(u << 16), __uint_as_float(u & 0xffff0000u));
}
__device__ __forceinline__ float2 unpk(unsigned u) {
  return make_float2(__uint_as_float(u << 16), __uint_as_float(u & 0xffff0000u));
}
__device__ __forceinline__ unsigned pk2(float x, float y) {
  bf16 bx = __float2bfloat16(x), by = __float2bfloat16(y);
  unsigned short ux, uy;
  __builtin_memcpy(&ux, &bx, 2);
  __builtin_memcpy(&uy, &by, 2);
  return (unsigned)ux | ((unsigned)uy << 16);
}

struct EdgeParams {
  const int* e[6];
  int E[6];
  int ebase[6];
  int nbase[6];
};

struct VSrc {
  const float* hf; const bf16* hh;
  const float* skf; const bf16* skh;
  const int* up;
  int nprev, Ch, Cs;
};

__device__ __forceinline__ float vloadf(const VSrc& s, int i, int c) {
  if (s.up) {
    if (c >= s.Ch) return s.skf[(long)i * s.Cs + (c - s.Ch)];
    if (i >= s.nprev) {
      int j = i - s.nprev;
      int u0 = s.up[2 * j], u1 = s.up[2 * j + 1];
      return 0.5f * (s.hf[(long)u0 * s.Ch + c] + s.hf[(long)u1 * s.Ch + c]);
    }
    return s.hf[(long)i * s.Ch + c];
  }
  return s.hf[(long)i * s.Ch + c];
}
__device__ __forceinline__ float2 vloadf2(const VSrc& s, int i, int c) {
  return make_float2(vloadf(s, i, c), vloadf(s, i, c + 1));
}

// ---------------- setup kernels ----------------
__global__ void k_fill(EdgeParams p, int* __restrict__ cnt, int2* __restrict__ ell, int ET) {
  for (int idx = blockIdx.x * blockDim.x + threadIdx.x; idx < ET; idx += gridDim.x * blockDim.x) {
    int l;
    if (idx < p.ebase[1]) l = 0;
    else if (idx < p.ebase[2]) l = 1;
    else if (idx < p.ebase[3]) l = 2;
    else if (idx < p.ebase[4]) l = 3;
    else if (idx < p.ebase[5]) l = 4;
    else l = 5;
    int e = idx - p.ebase[l];
    const int* epp = p.e[l];
    int row = epp[e];
    int col = epp[p.E[l] + e];
    int g = p.nbase[l] + row;
    int slot = atomicAdd(&cnt[g], 1);
    if (slot < MAXD) ell[g * MAXD + slot].x = col;
  }
}

__global__ void k_wfill(EdgeParams p, const int* __restrict__ cnt, int2* __restrict__ ell, int NT) {
  int total = NT * MAXD;
  for (int idx = blockIdx.x * blockDim.x + threadIdx.x; idx < total; idx += gridDim.x * blockDim.x) {
    int g = idx >> 5;
    int t = idx & (MAXD - 1);
    int dg = cnt[g];
    int d = dg < MAXD ? dg : MAXD;
    if (t < d) {
      int l;
      if (g < p.nbase[1]) l = 0;
      else if (g < p.nbase[2]) l = 1;
      else if (g < p.nbase[3]) l = 2;
      else if (g < p.nbase[4]) l = 3;
      else if (g < p.nbase[5]) l = 4;
      else l = 5;
      int c = ell[idx].x;
      int dc = cnt[p.nbase[l] + c];
      float w = (dc > 0) ? -(rsqrtf((float)dg) * rsqrtf((float)dc)) : 0.0f;
      ell[idx].y = __float_as_int(w);
    }
  }
}

// Repack W[3][Cin][Cout] -> Wp[3][Cin/4][Cout][4] for all 11 layers, PLUS x0 fp32->bf16.
struct WPack {
  const float* src[11];
  float* dst[11];
  int cin[11], cout[11], tot[11];
  const float* x0;
  bf16* x0h;
  int nx0;
};
__global__ void k_wpack(WPack P, int TOT) {
  int TALL = TOT + P.nx0;
  for (int idx = blockIdx.x * blockDim.x + threadIdx.x; idx < TALL; idx += gridDim.x * blockDim.x) {
    if (idx >= TOT) {
      int j = idx - TOT;
      P.x0h[j] = __float2bfloat16(P.x0[j]);
      continue;
    }
    int l = 0, off = idx;
    while (off >= P.tot[l]) { off -= P.tot[l]; ++l; }
    int cout = P.cout[l];
    int cinco = P.cin[l] * cout;
    int t = off / cinco;
    int rem = off - t * cinco;
    int k = rem / cout;
    int o = rem - k * cout;
    P.dst[l][((t * (P.cin[l] >> 2) + (k >> 2)) * cout + o) * 4 + (k & 3)] = P.src[l][off];
  }
}

// Materialize virtual upcat source into fp32 AND bf16 flat arrays.
__global__ void k_xmat2(VSrc src, float* __restrict__ Xf, bf16* __restrict__ Xh, int n, int Ctot) {
  int C2 = Ctot >> 1;
  int total = n * C2;
  for (int idx = blockIdx.x * blockDim.x + threadIdx.x; idx < total; idx += gridDim.x * blockDim.x) {
    int i = idx / C2;
    int c2 = idx - i * C2;
    float2 v = vloadf2(src, i, 2 * c2);
    long o = (long)i * Ctot + 2 * c2;
    *(float2*)(Xf + o) = v;
    *(unsigned*)(Xh + o) = pk2(v.x, v.y);
  }
}

// ---------------- big-layer gather kernels ----------------
__global__ void k_prop_flat(const bf16* __restrict__ Xh, float* __restrict__ T, bf16* __restrict__ Th,
                            const int* __restrict__ cnt, const int2* __restrict__ ell,
                            int nbase, int n, int C) {
  int C4 = C >> 2;
  int total = n * C4;
  for (int idx = blockIdx.x * blockDim.x + threadIdx.x; idx < total; idx += gridDim.x * blockDim.x) {
    int i = idx / C4;
    int c = (idx - i * C4) << 2;
    int g = nbase + i;
    int d = cnt[g]; if (d > MAXD) d = MAXD;
    const int2* cols = ell + (long)g * MAXD;
    float a0 = 0.f, a1 = 0.f, a2 = 0.f, a3 = 0.f;
    for (int t = 0; t < d; t += 8) {
      int ci[8]; float wj[8];
#pragma unroll
      for (int j = 0; j < 8; ++j) {
        int tt = t + j;
        int2 e = cols[(tt < d) ? tt : 0];
        ci[j] = e.x;
        wj[j] = (tt < d) ? __int_as_float(e.y) : 0.f;
      }
#pragma unroll
      for (int j = 0; j < 8; ++j) {
        uint2 raw = *(const uint2*)(Xh + (long)ci[j] * C + c);
        float2 v01 = unpk(raw.x);
        float2 v23 = unpk(raw.y);
        a0 += wj[j] * v01.x;
        a1 += wj[j] * v01.y;
        a2 += wj[j] * v23.x;
        a3 += wj[j] * v23.y;
      }
    }
    long o = (long)i * C + c;
    *(float4*)(T + o) = make_float4(a0, a1, a2, a3);
    uint2 pk; pk.x = pk2(a0, a1); pk.y = pk2(a2, a3);
    *(uint2*)(Th + o) = pk;
  }
}

// t2 = 2*A~t1 - x, x from FLAT fp32 X.
__global__ void k_prop2(const float* __restrict__ Xf, const bf16* __restrict__ T1h,
                        float* __restrict__ T2,
                        const int* __restrict__ cnt, const int2* __restrict__ ell,
                        int nbase, int n, int C) {
  int C4 = C >> 2;
  int total = n * C4;
  for (int idx = blockIdx.x * blockDim.x + threadIdx.x; idx < total; idx += gridDim.x * blockDim.x) {
    int i = idx / C4;
    int c = (idx - i * C4) << 2;
    int g = nbase + i;
    int d = cnt[g]; if (d > MAXD) d = MAXD;
    const int2* cols = ell + (long)g * MAXD;
    float a0 = 0.f, a1 = 0.f, a2 = 0.f, a3 = 0.f;
    for (int t = 0; t < d; t += 8) {
      int ci[8]; float wj[8];
#pragma unroll
      for (int j = 0; j < 8; ++j) {
        int tt = t + j;
        int2 e = cols[(tt < d) ? tt : 0];
        ci[j] = e.x;
        wj[j] = (tt < d) ? __int_as_float(e.y) : 0.f;
      }
#pragma unroll
      for (int j = 0; j < 8; ++j) {
        uint2 raw = *(const uint2*)(T1h + (long)ci[j] * C + c);
        float2 v01 = unpk(raw.x);
        float2 v23 = unpk(raw.y);
        a0 += wj[j] * v01.x;
        a1 += wj[j] * v01.y;
        a2 += wj[j] * v23.x;
        a3 += wj[j] * v23.y;
      }
    }
    float4 x = *(const float4*)(Xf + (long)i * C + c);
    long o = (long)i * C + c;
    *(float4*)(T2 + o) = make_float4(2.f * a0 - x.x, 2.f * a1 - x.y, 2.f * a2 - x.z, 2.f * a3 - x.w);
  }
}

// ---------------- big-layer combine: streams X, t1, t2 (+relu / +softmax) ----------------
template <int SMAX>
__global__ __launch_bounds__(256) void k_combine(
    const float* __restrict__ Xf, const float* __restrict__ T1, const float* __restrict__ T2s,
    const float4* __restrict__ Wp, const float* __restrict__ B,
    int n, int Cin, int Cout,
    float* __restrict__ OUT, bf16* __restrict__ OUTh) {
  constexpr int RPW = 2;  // ROWS=8, 4 row-groups
  __shared__ __align__(16) float sx[4][RPW][64];
  __shared__ __align__(16) float st1[4][RPW][64];
  __shared__ __align__(16) float st2[4][RPW][64];

  int tid = threadIdx.x;
  int w = tid >> 6;
  int lane = tid & 63;

  int colTiles = (Cout + 63) >> 6;
  int ct = blockIdx.x % colTiles;
  int rt = blockIdx.x / colTiles;
  int r0 = rt * 8 + w * RPW;
  int o = ct * 64 + lane;
  int oc = (o < Cout) ? o : (Cout - 1);
  int nch = (Cin + 63) >> 6;
  int KQ = Cin >> 2;

  float acc[RPW];
#pragma unroll
  for (int r = 0; r < RPW; ++r) acc[r] = 0.f;

  for (int c = 0; c < nch; ++c) {
    int k0 = c * 64;
    int kw = (Cin - k0 < 64) ? (Cin - k0) : 64;
    int k = k0 + lane;
    bool kv = lane < kw;

#pragma unroll
    for (int rr = 0; rr < RPW; ++rr) {
      int i = r0 + rr;
      bool iv = i < n;
      float xv = 0.f, tv = 0.f, t2v = 0.f;
      if (kv && iv) {
        xv = Xf[(long)i * Cin + k];
        tv = T1[(long)i * Cin + k];
        t2v = T2s[(long)i * Cin + k];
      }
      sx[w][rr][lane] = xv;
      st1[w][rr][lane] = tv;
      st2[w][rr][lane] = t2v;
    }
    __syncthreads();

    int kw4 = kw >> 2;
    for (int q = 0; q < kw4; ++q) {
      int kq = (k0 >> 2) + q;
      float4 w0 = Wp[(0 * KQ + kq) * Cout + oc];
      float4 w1 = Wp[(1 * KQ + kq) * Cout + oc];
      float4 w2 = Wp[(2 * KQ + kq) * Cout + oc];
#pragma unroll
      for (int rr = 0; rr < RPW; ++rr) {
        float4 xs = ((const float4*)sx[w][rr])[q];
        float4 t1s = ((const float4*)st1[w][rr])[q];
        float4 t2s = ((const float4*)st2[w][rr])[q];
        acc[rr] += w0.x * xs.x + w0.y * xs.y + w0.z * xs.z + w0.w * xs.w;
        acc[rr] += w1.x * t1s.x + w1.y * t1s.y + w1.z * t1s.z + w1.w * t1s.w;
        acc[rr] += w2.x * t2s.x + w2.y * t2s.y + w2.z * t2s.z + w2.w * t2s.w;
      }
    }
    __syncthreads();
  }

  if constexpr (SMAX) {
    float bb = (o < Cout) ? B[o] : 0.f;
#pragma unroll
    for (int rr = 0; rr < RPW; ++rr) {
      int i = r0 + rr;
      if (i < n) {
        float v = (o < Cout) ? (acc[rr] + bb) : -1e30f;
        float m = v;
        for (int s = 32; s > 0; s >>= 1) m = fmaxf(m, __shfl_xor(m, s));
        float e = (o < Cout) ? __expf(v - m) : 0.f;
        float sum = e;
        for (int s = 32; s > 0; s >>= 1) sum += __shfl_xor(sum, s);
        if (o < Cout) OUT[(long)i * Cout + o] = e / sum;
      }
    }
  } else {
    if (o < Cout) {
      float bb = B[oc];
#pragma unroll
      for (int rr = 0; rr < RPW; ++rr) {
        int i = r0 + rr;
        if (i < n) {
          float v = fmaxf(acc[rr] + bb, 0.f);
          long off = (long)i * Cout + o;
          OUT[off] = v;
          OUTh[off] = __float2bfloat16(v);
        }
      }
    }
  }
}

// ---------------- mid-layer fused cheb: t1 + two-hop t2 + GEMM, one kernel ----------------
// X flat (fp32 + bf16). Row-uniform ell/cnt loads are scalar; X gathers coalesce over lanes.
template <int ROWS, int CW>
__global__ __launch_bounds__(256) void k_cheb(
    const float* __restrict__ Xf, const bf16* __restrict__ Xh,
    const float4* __restrict__ Wp, const float* __restrict__ B,
    const int* __restrict__ cnt, const int2* __restrict__ ell,
    int nbase, int n, int Cin, int Cout,
    float* __restrict__ OUT, bf16* __restrict__ OUTh) {
  constexpr int RW = 4 / CW;
  constexpr int RPW = (ROWS * CW) / 4;
  static_assert(RPW * RW == ROWS, "bad ROWS/CW combo");

  __shared__ __align__(16) float sx[4][RPW][64];
  __shared__ __align__(16) float st1[4][RPW][64];
  __shared__ __align__(16) float st2[4][RPW][64];

  int tid = threadIdx.x;
  int w = tid >> 6;
  int lane = tid & 63;
  int rg = w / CW;
  int cw = w % CW;

  int colTiles = (Cout + 63) >> 6;
  int ct = blockIdx.x % colTiles;
  int rt = blockIdx.x / colTiles;
  int r0 = rt * ROWS + rg * RPW;
  int o = ct * 64 + lane;
  int oc = (o < Cout) ? o : (Cout - 1);
  int nch = Cin >> 6;  // mid layers: Cin % 64 == 0
  int KQ = Cin >> 2;

  float acc[RPW];
#pragma unroll
  for (int r = 0; r < RPW; ++r) acc[r] = 0.f;

  for (int cg = 0; cg < nch; cg += CW) {
    int c = cg + cw;
    bool act = c < nch;
    int k = c * 64 + lane;

#pragma unroll
    for (int rr = 0; rr < RPW; ++rr) {
      int i = r0 + rr;
      float xv = 0.f, t1v = 0.f, t2v = 0.f;
      if (act && i < n) {
        xv = Xf[(long)i * Cin + k];
        int g = nbase + i;
        int d = cnt[g]; if (d > MAXD) d = MAXD;
        const int2* cols = ell + (long)g * MAXD;
        float a2 = 0.f;
        for (int j = 0; j < d; ++j) {
          int2 e = cols[j];
          int cj = e.x;
          float wij = __int_as_float(e.y);
          t1v += wij * bf2f(Xh[(long)cj * Cin + k]);
          int gj = nbase + cj;
          int dj = cnt[gj]; if (dj > MAXD) dj = MAXD;
          const int2* cols2 = ell + (long)gj * MAXD;
          float tj = 0.f;
          for (int m = 0; m < dj; ++m) {
            int2 e2 = cols2[m];
            tj += __int_as_float(e2.y) * bf2f(Xh[(long)e2.x * Cin + k]);
          }
          a2 += wij * tj;
        }
        t2v = 2.f * a2 - xv;
      }
      sx[w][rr][lane] = xv;
      st1[w][rr][lane] = t1v;
      st2[w][rr][lane] = t2v;
    }
    __syncthreads();

    if (act) {
      int kqb = c << 4;  // (c*64)>>2
      // two 8-deep W-preload batches (kw4 == 16 for all mid layers)
      for (int qb = 0; qb < 16; qb += 8) {
        float4 wb0[8], wb1[8], wb2[8];
#pragma unroll
        for (int q = 0; q < 8; ++q) {
          int kq = kqb + qb + q;
          wb0[q] = Wp[(0 * KQ + kq) * Cout + oc];
          wb1[q] = Wp[(1 * KQ + kq) * Cout + oc];
          wb2[q] = Wp[(2 * KQ + kq) * Cout + oc];
        }
#pragma unroll
        for (int q = 0; q < 8; ++q) {
#pragma unroll
          for (int rr = 0; rr < RPW; ++rr) {
            float4 xs = ((const float4*)sx[w][rr])[qb + q];
            float4 t1s = ((const float4*)st1[w][rr])[qb + q];
            float4 t2s = ((const float4*)st2[w][rr])[qb + q];
            acc[rr] += wb0[q].x * xs.x + wb0[q].y * xs.y + wb0[q].z * xs.z + wb0[q].w * xs.w;
            acc[rr] += wb1[q].x * t1s.x + wb1[q].y * t1s.y + wb1[q].z * t1s.z + wb1[q].w * t1s.w;
            acc[rr] += wb2[q].x * t2s.x + wb2[q].y * t2s.y + wb2[q].z * t2s.z + wb2[q].w * t2s.w;
          }
        }
      }
    }
    __syncthreads();
  }

  if constexpr (CW == 1) {
    if (o < Cout) {
      float bb = B[oc];
#pragma unroll
      for (int rr = 0; rr < RPW; ++rr) {
        int i = r0 + rr;
        if (i < n) {
          float v = fmaxf(acc[rr] + bb, 0.f);
          long off = (long)i * Cout + o;
          OUT[off] = v;
          OUTh[off] = __float2bfloat16(v);
        }
      }
    }
  } else {
#pragma unroll
    for (int rr = 0; rr < RPW; ++rr) sx[w][rr][lane] = acc[rr];
    __syncthreads();
    if (cw == 0 && o < Cout) {
      float bb = B[oc];
#pragma unroll
      for (int rr = 0; rr < RPW; ++rr) {
        int i = r0 + rr;
        if (i < n) {
          float v = bb;
#pragma unroll
          for (int j = 0; j < CW; ++j) v += sx[rg * CW + j][rr][lane];
          v = fmaxf(v, 0.f);
          long off = (long)i * Cout + o;
          OUT[off] = v;
          OUTh[off] = __float2bfloat16(v);
        }
      }
    }
  }
}

// ---------------- launcher ----------------
extern "C" void kernel_launch(void* const* d_in, const int* in_sizes, int n_in,
                              void* d_out, int out_size, void* d_ws, size_t ws_size,
                              hipStream_t stream) {
  static const int NV[6] = {42, 162, 642, 2562, 10242, 40962};
  static const int NE[6] = {240, 960, 3840, 15360, 61440, 245760};
  const int NT = 54612;
  const int ET = 327600;

  EdgeParams ep;
  {
    int nb = 0, eb = 0;
    for (int l = 0; l < 6; ++l) {
      ep.e[l] = (const int*)d_in[1 + l];
      ep.E[l] = NE[l];
      ep.ebase[l] = eb;
      ep.nbase[l] = nb;
      eb += NE[l];
      nb += NV[l];
    }
  }
  const float* x0f = (const float*)d_in[0];
  const int* up[5];
  for (int i = 0; i < 5; ++i) up[i] = (const int*)d_in[7 + i];  // up2..up6
  const float *W[11], *Bb[11];
  for (int i = 0; i < 11; ++i) {
    W[i] = (const float*)d_in[12 + 2 * i];
    Bb[i] = (const float*)d_in[13 + 2 * i];
  }
  static const int LCI[11] = {4, 32, 64, 128, 256, 512, 768, 384, 192, 96, 36};
  static const int LCO[11] = {32, 64, 128, 256, 512, 512, 256, 128, 64, 32, 37};

  // ---- workspace carve (16B-aligned) ----
  char* p = (char*)d_ws;
  auto alloc_b = [&](size_t bytes) { void* r = (void*)p; p += (bytes + 15) & ~size_t(15); return r; };
  auto alloc_i = [&](size_t ne) { return (int*)alloc_b(ne * 4); };
  auto alloc_f = [&](size_t ne) { return (float*)alloc_b(ne * 4); };
  auto alloc_h = [&](size_t ne) { return (bf16*)alloc_b(ne * 2); };
  int* cnt = alloc_i(NT);
  int2* ell = (int2*)alloc_b((size_t)NT * MAXD * 8);
  float* t1f = alloc_f((size_t)40962 * 36);
  bf16* t1h = alloc_h((size_t)40962 * 36);
  float* t2f = alloc_f((size_t)40962 * 36);
  bf16* x0h = alloc_h((size_t)40962 * 4);
  float* xf = alloc_f((size_t)40962 * 36);  // materialized upcat X (fp32), reused across layers
  bf16* xh = alloc_h((size_t)40962 * 36);   // bf16 shadow
  float* wp[11];
  for (int i = 0; i < 11; ++i) wp[i] = alloc_f((size_t)3 * LCI[i] * LCO[i]);
  float *af[10]; bf16 *ah[10];
  const int an[10] = {40962, 10242, 2562, 642, 162, 42, 162, 642, 2562, 10242};
  const int ac[10] = {32, 64, 128, 256, 512, 512, 256, 128, 64, 32};
  for (int i = 0; i < 10; ++i) {
    af[i] = alloc_f((size_t)an[i] * ac[i]);
    ah[i] = alloc_h((size_t)an[i] * ac[i]);
  }

  hipMemsetAsync(cnt, 0, (size_t)NT * 4, stream);
  k_fill<<<(ET + 255) / 256, 256, 0, stream>>>(ep, cnt, ell, ET);
  k_wfill<<<(NT * MAXD + 255) / 256, 256, 0, stream>>>(ep, cnt, ell, NT);
  {
    WPack P;
    int TOT = 0;
    for (int i = 0; i < 11; ++i) {
      P.src[i] = W[i];
      P.dst[i] = wp[i];
      P.cin[i] = LCI[i];
      P.cout[i] = LCO[i];
      P.tot[i] = 3 * LCI[i] * LCO[i];
      TOT += P.tot[i];
    }
    P.x0 = x0f; P.x0h = x0h; P.nx0 = 40962 * 4;
    k_wpack<<<(TOT + P.nx0 + 255) / 256, 256, 0, stream>>>(P, TOT);
  }

  auto upsrc = [](const float* hf, const float* skf, const int* u, int nprev, int Ch, int Cs) {
    VSrc s{hf, nullptr, skf, nullptr, u, nprev, Ch, Cs}; return s;
  };

  // big layer: prop_flat + prop2 + streaming combine
  auto big = [&](const float* Xf, const bf16* Xh, float* OUT, bf16* OUTh, int lvl, int n,
                 int Cin, int Cout, const float* Wq, const float* Bp, int smax) {
    int nb = ep.nbase[lvl];
    int t4 = n * (Cin >> 2);
    k_prop_flat<<<(t4 + 255) / 256, 256, 0, stream>>>(Xh, t1f, t1h, cnt, ell, nb, n, Cin);
    k_prop2<<<(t4 + 255) / 256, 256, 0, stream>>>(Xf, t1h, t2f, cnt, ell, nb, n, Cin);
    int grid = ((Cout + 63) / 64) * ((n + 7) / 8);
    if (smax)
      k_combine<1><<<grid, 256, 0, stream>>>(Xf, t1f, t2f, (const float4*)Wq, Bp, n, Cin, Cout, OUT, OUTh);
    else
      k_combine<0><<<grid, 256, 0, stream>>>(Xf, t1f, t2f, (const float4*)Wq, Bp, n, Cin, Cout, OUT, OUTh);
  };

  // mid layer: single fused cheb kernel on flat X
#define MIDC(RS, CWv, Xff, Xhh, OUT, OUTh, lvl, n, Cin, Cout, Wq, Bp)                          \
  {                                                                                            \
    int nb = ep.nbase[lvl];                                                                    \
    int grid = (((Cout) + 63) / 64) * (((n) + (RS)-1) / (RS));                                 \
    k_cheb<RS, CWv><<<grid, 256, 0, stream>>>(Xff, Xhh, (const float4*)Wq, Bp, cnt, ell, nb,   \
                                              n, Cin, Cout, OUT, OUTh);                        \
  }

  // ---- L1: n=40962, 4->32 ----
  big(x0f, x0h, af[0], ah[0], 5, 40962, 4, 32, wp[0], Bb[0], 0);
  // ---- L2: n=10242, 32->64 ----
  big(af[0], ah[0], af[1], ah[1], 4, 10242, 32, 64, wp[1], Bb[1], 0);
  // ---- mid encoder (flat inputs already) ----
  MIDC(4, 1, af[1], ah[1], af[2], ah[2], 3, 2562, 64, 128, wp[2], Bb[2]);
  MIDC(2, 2, af[2], ah[2], af[3], ah[3], 2, 642, 128, 256, wp[3], Bb[3]);
  MIDC(1, 4, af[3], ah[3], af[4], ah[4], 1, 162, 256, 512, wp[4], Bb[4]);
  MIDC(1, 4, af[4], ah[4], af[5], ah[5], 0, 42, 512, 512, wp[5], Bb[5]);
  // ---- mid decoder: materialize upcat X, then fused cheb ----
  {
    VSrc s = upsrc(af[5], af[3], up[0], 42, 512, 256);
    k_xmat2<<<(162 * 384 + 255) / 256, 256, 0, stream>>>(s, xf, xh, 162, 768);
    MIDC(1, 4, xf, xh, af[6], ah[6], 1, 162, 768, 256, wp[6], Bb[6]);
  }
  {
    VSrc s = upsrc(af[6], af[2], up[1], 162, 256, 128);
    k_xmat2<<<(642 * 192 + 255) / 256, 256, 0, stream>>>(s, xf, xh, 642, 384);
    MIDC(2, 4, xf, xh, af[7], ah[7], 2, 642, 384, 128, wp[7], Bb[7]);
  }
  {
    VSrc s = upsrc(af[7], af[1], up[2], 642, 128, 64);
    k_xmat2<<<(2562 * 96 + 255) / 256, 256, 0, stream>>>(s, xf, xh, 2562, 192);
    MIDC(2, 4, xf, xh, af[8], ah[8], 3, 2562, 192, 64, wp[8], Bb[8]);
  }
  // ---- L10: n=10242, [64|32]->32 ----
  {
    VSrc s = upsrc(af[8], af[0], up[3], 2562, 64, 32);
    k_xmat2<<<(10242 * 48 + 255) / 256, 256, 0, stream>>>(s, xf, xh, 10242, 96);
    big(xf, xh, af[9], ah[9], 4, 10242, 96, 32, wp[9], Bb[9], 0);
  }
  // ---- L11: n=40962, [32|4]->37 + softmax ----
  {
    VSrc s = upsrc(af[9], x0f, up[4], 10242, 32, 4);
    k_xmat2<<<(40962 * 18 + 255) / 256, 256, 0, stream>>>(s, xf, xh, 40962, 36);
    big(xf, xh, (float*)d_out, nullptr, 5, 40962, 36, 37, wp[10], Bb[10], 1);
  }
}

// Round 13
// 528.241 us; speedup vs baseline: 1.3292x; 1.3292x over previous
//
#include <hip/hip_runtime.h>
#include <hip/hip_bf16.h>

#define MAXD 32
typedef __hip_bfloat16 bf16;

__device__ __forceinline__ float bf2f(bf16 v) { return __bfloat162float(v); }
__device__ __forceinline__ float2 ldbf2(const bf16* p) {
  unsigned u = *(const unsigned*)p;
  return make_float2(__uint_as_float(u << 16), __uint_as_float(u & 0xffff0000u));
}
__device__ __forceinline__ float2 unpk(unsigned u) {
  return make_float2(__uint_as_float(u << 16), __uint_as_float(u & 0xffff0000u));
}
__device__ __forceinline__ unsigned pk2(float x, float y) {
  bf16 bx = __float2bfloat16(x), by = __float2bfloat16(y);
  unsigned short ux, uy;
  __builtin_memcpy(&ux, &bx, 2);
  __builtin_memcpy(&uy, &by, 2);
  return (unsigned)ux | ((unsigned)uy << 16);
}

struct EdgeParams {
  const int* e[6];
  int E[6];
  int ebase[6];
  int nbase[6];
};

struct VSrc {
  const float* hf; const bf16* hh;
  const float* skf; const bf16* skh;
  const int* up;
  int nprev, Ch, Cs;
};

__device__ __forceinline__ float vloadf(const VSrc& s, int i, int c) {
  if (s.up) {
    if (c >= s.Ch) return s.skf[(long)i * s.Cs + (c - s.Ch)];
    if (i >= s.nprev) {
      int j = i - s.nprev;
      int u0 = s.up[2 * j], u1 = s.up[2 * j + 1];
      return 0.5f * (s.hf[(long)u0 * s.Ch + c] + s.hf[(long)u1 * s.Ch + c]);
    }
    return s.hf[(long)i * s.Ch + c];
  }
  return s.hf[(long)i * s.Ch + c];
}

__device__ __forceinline__ float2 vloadh2(const VSrc& s, int i, int c2) {
  int c = 2 * c2;
  if (s.up) {
    if (c >= s.Ch) return ldbf2(s.skh + (long)i * s.Cs + (c - s.Ch));
    if (i >= s.nprev) {
      int j = i - s.nprev;
      int u0 = s.up[2 * j], u1 = s.up[2 * j + 1];
      float2 a = ldbf2(s.hh + (long)u0 * s.Ch + c);
      float2 b = ldbf2(s.hh + (long)u1 * s.Ch + c);
      return make_float2(0.5f * (a.x + b.x), 0.5f * (a.y + b.y));
    }
    return ldbf2(s.hh + (long)i * s.Ch + c);
  }
  return ldbf2(s.hh + (long)i * s.Ch + c);
}

// fp32 pair via fp32 sources (for xmat2)
__device__ __forceinline__ float2 vloadf2(const VSrc& s, int i, int c) {
  return make_float2(vloadf(s, i, c), vloadf(s, i, c + 1));
}

// ---------------- setup kernels ----------------
__global__ void k_fill(EdgeParams p, int* __restrict__ cnt, int2* __restrict__ ell, int ET) {
  for (int idx = blockIdx.x * blockDim.x + threadIdx.x; idx < ET; idx += gridDim.x * blockDim.x) {
    int l;
    if (idx < p.ebase[1]) l = 0;
    else if (idx < p.ebase[2]) l = 1;
    else if (idx < p.ebase[3]) l = 2;
    else if (idx < p.ebase[4]) l = 3;
    else if (idx < p.ebase[5]) l = 4;
    else l = 5;
    int e = idx - p.ebase[l];
    const int* epp = p.e[l];
    int row = epp[e];
    int col = epp[p.E[l] + e];
    int g = p.nbase[l] + row;
    int slot = atomicAdd(&cnt[g], 1);
    if (slot < MAXD) ell[g * MAXD + slot].x = col;
  }
}

__global__ void k_wfill(EdgeParams p, const int* __restrict__ cnt, int2* __restrict__ ell, int NT) {
  int total = NT * MAXD;
  for (int idx = blockIdx.x * blockDim.x + threadIdx.x; idx < total; idx += gridDim.x * blockDim.x) {
    int g = idx >> 5;
    int t = idx & (MAXD - 1);
    int dg = cnt[g];
    int d = dg < MAXD ? dg : MAXD;
    if (t < d) {
      int l;
      if (g < p.nbase[1]) l = 0;
      else if (g < p.nbase[2]) l = 1;
      else if (g < p.nbase[3]) l = 2;
      else if (g < p.nbase[4]) l = 3;
      else if (g < p.nbase[5]) l = 4;
      else l = 5;
      int c = ell[idx].x;
      int dc = cnt[p.nbase[l] + c];
      float w = (dc > 0) ? -(rsqrtf((float)dg) * rsqrtf((float)dc)) : 0.0f;
      ell[idx].y = __float_as_int(w);
    }
  }
}

__global__ void k_cvt(const float* __restrict__ in, bf16* __restrict__ out, int N) {
  for (int i = blockIdx.x * blockDim.x + threadIdx.x; i < N; i += gridDim.x * blockDim.x)
    out[i] = __float2bfloat16(in[i]);
}

// Repack W[3][Cin][Cout] -> Wp[3][Cin/4][Cout][4] (k-grouped float4), all 11 layers.
struct WPack {
  const float* src[11];
  float* dst[11];
  int cin[11], cout[11], tot[11];
};
__global__ void k_wpack(WPack P, int TOT) {
  for (int idx = blockIdx.x * blockDim.x + threadIdx.x; idx < TOT; idx += gridDim.x * blockDim.x) {
    int l = 0, off = idx;
    while (off >= P.tot[l]) { off -= P.tot[l]; ++l; }
    int cout = P.cout[l];
    int cinco = P.cin[l] * cout;
    int t = off / cinco;
    int rem = off - t * cinco;
    int k = rem / cout;
    int o = rem - k * cout;
    P.dst[l][((t * (P.cin[l] >> 2) + (k >> 2)) * cout + o) * 4 + (k & 3)] = P.src[l][off];
  }
}

// Materialize virtual upcat source into fp32 AND bf16 flat arrays.
__global__ void k_xmat2(VSrc src, float* __restrict__ Xf, bf16* __restrict__ Xh, int n, int Ctot) {
  int C2 = Ctot >> 1;
  int total = n * C2;
  for (int idx = blockIdx.x * blockDim.x + threadIdx.x; idx < total; idx += gridDim.x * blockDim.x) {
    int i = idx / C2;
    int c2 = idx - i * C2;
    float2 v = vloadf2(src, i, 2 * c2);
    long o = (long)i * Ctot + 2 * c2;
    *(float2*)(Xf + o) = v;
    *(unsigned*)(Xh + o) = pk2(v.x, v.y);
  }
}

// ---------------- big-layer gather kernels (2 rows/thread: 16 loads in flight) ----------------
// NOTE: gather index must be clamped to 0 for slots past the row's degree — slot 0 of a
// degree-0 row is NEVER initialized by k_fill (holds 0xAA poison -> faulting address).
__global__ void k_prop_flat(const bf16* __restrict__ Xh, float* __restrict__ T, bf16* __restrict__ Th,
                            const int* __restrict__ cnt, const int2* __restrict__ ell,
                            int nbase, int n, int C) {
  int C4 = C >> 2;
  int total = (n >> 1) * C4;  // n even for all big layers
  for (int idx = blockIdx.x * blockDim.x + threadIdx.x; idx < total; idx += gridDim.x * blockDim.x) {
    int ip = idx / C4;
    int c = (idx - ip * C4) << 2;
    int i0 = ip << 1, i1 = i0 + 1;
    int g0 = nbase + i0, g1 = nbase + i1;
    int d0 = cnt[g0]; if (d0 > MAXD) d0 = MAXD;
    int d1 = cnt[g1]; if (d1 > MAXD) d1 = MAXD;
    const int2* cols0 = ell + (long)g0 * MAXD;
    const int2* cols1 = ell + (long)g1 * MAXD;
    float a0 = 0.f, a1 = 0.f, a2 = 0.f, a3 = 0.f;
    float b0 = 0.f, b1 = 0.f, b2 = 0.f, b3 = 0.f;
    int dm = d0 > d1 ? d0 : d1;
    for (int t = 0; t < dm; t += 8) {
      int ciA[8], ciB[8]; float wA[8], wB[8];
#pragma unroll
      for (int j = 0; j < 8; ++j) {
        int tt = t + j;
        int2 eA = cols0[(tt < d0) ? tt : 0];
        int2 eB = cols1[(tt < d1) ? tt : 0];
        ciA[j] = (tt < d0) ? eA.x : 0;
        wA[j] = (tt < d0) ? __int_as_float(eA.y) : 0.f;
        ciB[j] = (tt < d1) ? eB.x : 0;
        wB[j] = (tt < d1) ? __int_as_float(eB.y) : 0.f;
      }
#pragma unroll
      for (int j = 0; j < 8; ++j) {
        uint2 rA = *(const uint2*)(Xh + (long)ciA[j] * C + c);
        uint2 rB = *(const uint2*)(Xh + (long)ciB[j] * C + c);
        float2 vA01 = unpk(rA.x), vA23 = unpk(rA.y);
        float2 vB01 = unpk(rB.x), vB23 = unpk(rB.y);
        a0 += wA[j] * vA01.x; a1 += wA[j] * vA01.y; a2 += wA[j] * vA23.x; a3 += wA[j] * vA23.y;
        b0 += wB[j] * vB01.x; b1 += wB[j] * vB01.y; b2 += wB[j] * vB23.x; b3 += wB[j] * vB23.y;
      }
    }
    long o0 = (long)i0 * C + c;
    long o1 = (long)i1 * C + c;
    *(float4*)(T + o0) = make_float4(a0, a1, a2, a3);
    *(float4*)(T + o1) = make_float4(b0, b1, b2, b3);
    uint2 pA; pA.x = pk2(a0, a1); pA.y = pk2(a2, a3);
    uint2 pB; pB.x = pk2(b0, b1); pB.y = pk2(b2, b3);
    *(uint2*)(Th + o0) = pA;
    *(uint2*)(Th + o1) = pB;
  }
}

// t2 = 2*A~t1 - x, x from FLAT fp32 X; 2 rows/thread.
__global__ void k_prop2(const float* __restrict__ Xf, const bf16* __restrict__ T1h,
                        float* __restrict__ T2,
                        const int* __restrict__ cnt, const int2* __restrict__ ell,
                        int nbase, int n, int C) {
  int C4 = C >> 2;
  int total = (n >> 1) * C4;
  for (int idx = blockIdx.x * blockDim.x + threadIdx.x; idx < total; idx += gridDim.x * blockDim.x) {
    int ip = idx / C4;
    int c = (idx - ip * C4) << 2;
    int i0 = ip << 1, i1 = i0 + 1;
    int g0 = nbase + i0, g1 = nbase + i1;
    int d0 = cnt[g0]; if (d0 > MAXD) d0 = MAXD;
    int d1 = cnt[g1]; if (d1 > MAXD) d1 = MAXD;
    const int2* cols0 = ell + (long)g0 * MAXD;
    const int2* cols1 = ell + (long)g1 * MAXD;
    float a0 = 0.f, a1 = 0.f, a2 = 0.f, a3 = 0.f;
    float b0 = 0.f, b1 = 0.f, b2 = 0.f, b3 = 0.f;
    int dm = d0 > d1 ? d0 : d1;
    for (int t = 0; t < dm; t += 8) {
      int ciA[8], ciB[8]; float wA[8], wB[8];
#pragma unroll
      for (int j = 0; j < 8; ++j) {
        int tt = t + j;
        int2 eA = cols0[(tt < d0) ? tt : 0];
        int2 eB = cols1[(tt < d1) ? tt : 0];
        ciA[j] = (tt < d0) ? eA.x : 0;
        wA[j] = (tt < d0) ? __int_as_float(eA.y) : 0.f;
        ciB[j] = (tt < d1) ? eB.x : 0;
        wB[j] = (tt < d1) ? __int_as_float(eB.y) : 0.f;
      }
#pragma unroll
      for (int j = 0; j < 8; ++j) {
        uint2 rA = *(const uint2*)(T1h + (long)ciA[j] * C + c);
        uint2 rB = *(const uint2*)(T1h + (long)ciB[j] * C + c);
        float2 vA01 = unpk(rA.x), vA23 = unpk(rA.y);
        float2 vB01 = unpk(rB.x), vB23 = unpk(rB.y);
        a0 += wA[j] * vA01.x; a1 += wA[j] * vA01.y; a2 += wA[j] * vA23.x; a3 += wA[j] * vA23.y;
        b0 += wB[j] * vB01.x; b1 += wB[j] * vB01.y; b2 += wB[j] * vB23.x; b3 += wB[j] * vB23.y;
      }
    }
    long o0 = (long)i0 * C + c;
    long o1 = (long)i1 * C + c;
    float4 x0 = *(const float4*)(Xf + o0);
    float4 x1 = *(const float4*)(Xf + o1);
    *(float4*)(T2 + o0) = make_float4(2.f * a0 - x0.x, 2.f * a1 - x0.y, 2.f * a2 - x0.z, 2.f * a3 - x0.w);
    *(float4*)(T2 + o1) = make_float4(2.f * b0 - x1.x, 2.f * b1 - x1.y, 2.f * b2 - x1.z, 2.f * b3 - x1.w);
  }
}

// mid-layer t1 gather from virtual source; pair of channels/thread.
__global__ void k_prop_v(VSrc src, float* __restrict__ T, bf16* __restrict__ Th,
                         const int* __restrict__ cnt, const int2* __restrict__ ell,
                         int nbase, int n, int C) {
  int C2 = C >> 1;
  int total = n * C2;
  for (int idx = blockIdx.x * blockDim.x + threadIdx.x; idx < total; idx += gridDim.x * blockDim.x) {
    int i = idx / C2;
    int c2 = idx - i * C2;
    int g = nbase + i;
    int d = cnt[g]; if (d > MAXD) d = MAXD;
    const int2* cols = ell + (long)g * MAXD;
    float ax = 0.f, ay = 0.f;
    for (int t = 0; t < d; t += 8) {
      int ci[8]; float wj[8];
#pragma unroll
      for (int j = 0; j < 8; ++j) {
        int tt = t + j;
        int2 e = cols[(tt < d) ? tt : 0];
        ci[j] = e.x;
        wj[j] = (tt < d) ? __int_as_float(e.y) : 0.f;
      }
#pragma unroll
      for (int j = 0; j < 8; ++j) {
        float2 v = vloadh2(src, ci[j], c2);
        ax += wj[j] * v.x;
        ay += wj[j] * v.y;
      }
    }
    long o = (long)i * C + 2 * c2;
    ((float2*)T)[o >> 1] = make_float2(ax, ay);
    *(unsigned*)(Th + o) = pk2(ax, ay);
  }
}

// ---------------- combine: [X|t1|t2] @ Wp + b (+relu / +softmax) ----------------
// Wp is k-grouped float4: [3][Cin/4][Cout][4].
// GATHER=1: t2 gathered from T1h; GATHER=0: t2 streamed from T2s.
// BATCH=1: 8-deep W preload (for L2-cold big W); BATCH=0: simple loop (low VGPR).
template <int ROWS, int CW, int SMAX, int GATHER, int BATCH>
__global__ __launch_bounds__(256) void k_combine(
    VSrc src, const float* __restrict__ T1, const bf16* __restrict__ T1h,
    const float* __restrict__ T2s,
    const float4* __restrict__ Wp, const float* __restrict__ B,
    const int* __restrict__ cnt, const int2* __restrict__ ell,
    int nbase, int n, int Cin, int Cout, int doRelu,
    float* __restrict__ OUT, bf16* __restrict__ OUTh) {
  constexpr int RW = 4 / CW;
  constexpr int RPW = (ROWS * CW) / 4;
  static_assert(RPW * RW == ROWS, "bad ROWS/CW combo");

  __shared__ __align__(16) float sx[4][RPW][64];
  __shared__ __align__(16) float st1[4][RPW][64];
  __shared__ __align__(16) float st2[4][RPW][64];

  int tid = threadIdx.x;
  int w = tid >> 6;
  int lane = tid & 63;
  int rg = w / CW;
  int cw = w % CW;

  int colTiles = (Cout + 63) >> 6;
  int ct = blockIdx.x % colTiles;
  int rt = blockIdx.x / colTiles;
  int r0 = rt * ROWS + rg * RPW;
  int o = ct * 64 + lane;
  int oc = (o < Cout) ? o : (Cout - 1);
  int nch = (Cin + 63) >> 6;
  int KQ = Cin >> 2;

  float acc[RPW];
#pragma unroll
  for (int r = 0; r < RPW; ++r) acc[r] = 0.f;

  for (int cg = 0; cg < nch; cg += CW) {
    int c = cg + cw;
    bool act = c < nch;
    int k0 = c * 64;
    int kw = act ? ((Cin - k0 < 64) ? (Cin - k0) : 64) : 0;
    int k = k0 + lane;
    bool kv = act && (lane < kw);

#pragma unroll
    for (int rr = 0; rr < RPW; ++rr) {
      int i = r0 + rr;
      bool iv = i < n;
      float xv = 0.f, tv = 0.f, t2v = 0.f;
      if (kv && iv) {
        xv = vloadf(src, i, k);
        tv = T1[(long)i * Cin + k];
        if constexpr (GATHER) {
          int g = nbase + i;
          int d = cnt[g]; if (d > MAXD) d = MAXD;
          const int2* cols = ell + (long)g * MAXD;
          float a2 = 0.f;
          for (int t = 0; t < d; t += 8) {
            int ci[8]; float wj[8];
#pragma unroll
            for (int j = 0; j < 8; ++j) {
              int tt = t + j;
              int2 e = cols[(tt < d) ? tt : 0];
              ci[j] = e.x;
              wj[j] = (tt < d) ? __int_as_float(e.y) : 0.f;
            }
#pragma unroll
            for (int j = 0; j < 8; ++j)
              a2 += wj[j] * bf2f(T1h[(long)ci[j] * Cin + k]);
          }
          t2v = 2.f * a2 - xv;
        } else {
          t2v = T2s[(long)i * Cin + k];
        }
      }
      sx[w][rr][lane] = xv;
      st1[w][rr][lane] = tv;
      st2[w][rr][lane] = t2v;
    }
    __syncthreads();

    int kw4 = kw >> 2;
    int kqb = k0 >> 2;
    int qb = 0;
    if constexpr (BATCH) {
      // preload 8 q-iters of W (24 float4) then compute — keeps 23 loads in flight
      for (; qb + 8 <= kw4; qb += 8) {
        float4 wb0[8], wb1[8], wb2[8];
#pragma unroll
        for (int q = 0; q < 8; ++q) {
          int kq = kqb + qb + q;
          wb0[q] = Wp[(0 * KQ + kq) * Cout + oc];
          wb1[q] = Wp[(1 * KQ + kq) * Cout + oc];
          wb2[q] = Wp[(2 * KQ + kq) * Cout + oc];
        }
#pragma unroll
        for (int q = 0; q < 8; ++q) {
#pragma unroll
          for (int rr = 0; rr < RPW; ++rr) {
            float4 xs = ((const float4*)sx[w][rr])[qb + q];
            float4 t1s = ((const float4*)st1[w][rr])[qb + q];
            float4 t2s = ((const float4*)st2[w][rr])[qb + q];
            acc[rr] += wb0[q].x * xs.x + wb0[q].y * xs.y + wb0[q].z * xs.z + wb0[q].w * xs.w;
            acc[rr] += wb1[q].x * t1s.x + wb1[q].y * t1s.y + wb1[q].z * t1s.z + wb1[q].w * t1s.w;
            acc[rr] += wb2[q].x * t2s.x + wb2[q].y * t2s.y + wb2[q].z * t2s.z + wb2[q].w * t2s.w;
          }
        }
      }
    }
    for (int q = qb; q < kw4; ++q) {
      int kq = kqb + q;
      float4 w0 = Wp[(0 * KQ + kq) * Cout + oc];
      float4 w1 = Wp[(1 * KQ + kq) * Cout + oc];
      float4 w2 = Wp[(2 * KQ + kq) * Cout + oc];
#pragma unroll
      for (int rr = 0; rr < RPW; ++rr) {
        float4 xs = ((const float4*)sx[w][rr])[q];
        float4 t1s = ((const float4*)st1[w][rr])[q];
        float4 t2s = ((const float4*)st2[w][rr])[q];
        acc[rr] += w0.x * xs.x + w0.y * xs.y + w0.z * xs.z + w0.w * xs.w;
        acc[rr] += w1.x * t1s.x + w1.y * t1s.y + w1.z * t1s.z + w1.w * t1s.w;
        acc[rr] += w2.x * t2s.x + w2.y * t2s.y + w2.z * t2s.z + w2.w * t2s.w;
      }
    }
    __syncthreads();
  }

  if constexpr (SMAX) {
    float bb = (o < Cout) ? B[o] : 0.f;
#pragma unroll
    for (int rr = 0; rr < RPW; ++rr) {
      int i = r0 + rr;
      if (i < n) {
        float v = (o < Cout) ? (acc[rr] + bb) : -1e30f;
        float m = v;
        for (int s = 32; s > 0; s >>= 1) m = fmaxf(m, __shfl_xor(m, s));
        float e = (o < Cout) ? __expf(v - m) : 0.f;
        float sum = e;
        for (int s = 32; s > 0; s >>= 1) sum += __shfl_xor(sum, s);
        if (o < Cout) OUT[(long)i * Cout + o] = e / sum;
      }
    }
  } else if constexpr (CW == 1) {
    if (o < Cout) {
      float bb = B[oc];
#pragma unroll
      for (int rr = 0; rr < RPW; ++rr) {
        int i = r0 + rr;
        if (i < n) {
          float v = acc[rr] + bb;
          if (doRelu) v = fmaxf(v, 0.f);
          long off = (long)i * Cout + o;
          OUT[off] = v;
          OUTh[off] = __float2bfloat16(v);
        }
      }
    }
  } else {
#pragma unroll
    for (int rr = 0; rr < RPW; ++rr) sx[w][rr][lane] = acc[rr];
    __syncthreads();
    if (cw == 0 && o < Cout) {
      float bb = B[oc];
#pragma unroll
      for (int rr = 0; rr < RPW; ++rr) {
        int i = r0 + rr;
        if (i < n) {
          float v = bb;
#pragma unroll
          for (int j = 0; j < CW; ++j) v += sx[rg * CW + j][rr][lane];
          if (doRelu) v = fmaxf(v, 0.f);
          long off = (long)i * Cout + o;
          OUT[off] = v;
          OUTh[off] = __float2bfloat16(v);
        }
      }
    }
  }
}

// ---------------- launcher ----------------
extern "C" void kernel_launch(void* const* d_in, const int* in_sizes, int n_in,
                              void* d_out, int out_size, void* d_ws, size_t ws_size,
                              hipStream_t stream) {
  static const int NV[6] = {42, 162, 642, 2562, 10242, 40962};
  static const int NE[6] = {240, 960, 3840, 15360, 61440, 245760};
  const int NT = 54612;
  const int ET = 327600;

  EdgeParams ep;
  {
    int nb = 0, eb = 0;
    for (int l = 0; l < 6; ++l) {
      ep.e[l] = (const int*)d_in[1 + l];
      ep.E[l] = NE[l];
      ep.ebase[l] = eb;
      ep.nbase[l] = nb;
      eb += NE[l];
      nb += NV[l];
    }
  }
  const float* x0f = (const float*)d_in[0];
  const int* up[5];
  for (int i = 0; i < 5; ++i) up[i] = (const int*)d_in[7 + i];  // up2..up6
  const float *W[11], *Bb[11];
  for (int i = 0; i < 11; ++i) {
    W[i] = (const float*)d_in[12 + 2 * i];
    Bb[i] = (const float*)d_in[13 + 2 * i];
  }
  static const int LCI[11] = {4, 32, 64, 128, 256, 512, 768, 384, 192, 96, 36};
  static const int LCO[11] = {32, 64, 128, 256, 512, 512, 256, 128, 64, 32, 37};

  // ---- workspace carve (16B-aligned) ----
  char* p = (char*)d_ws;
  auto alloc_b = [&](size_t bytes) { void* r = (void*)p; p += (bytes + 15) & ~size_t(15); return r; };
  auto alloc_i = [&](size_t ne) { return (int*)alloc_b(ne * 4); };
  auto alloc_f = [&](size_t ne) { return (float*)alloc_b(ne * 4); };
  auto alloc_h = [&](size_t ne) { return (bf16*)alloc_b(ne * 2); };
  int* cnt = alloc_i(NT);
  int2* ell = (int2*)alloc_b((size_t)NT * MAXD * 8);
  float* t1f = alloc_f((size_t)40962 * 36);
  bf16* t1h = alloc_h((size_t)40962 * 36);
  float* t2f = alloc_f((size_t)40962 * 36);
  bf16* x0h = alloc_h((size_t)40962 * 4);
  float* xf = alloc_f((size_t)40962 * 36);  // L10/L11 materialized fp32 X
  bf16* xh = alloc_h((size_t)40962 * 36);   // and bf16 shadow
  float* wp[11];
  for (int i = 0; i < 11; ++i) wp[i] = alloc_f((size_t)3 * LCI[i] * LCO[i]);
  float *af[10]; bf16 *ah[10];
  const int an[10] = {40962, 10242, 2562, 642, 162, 42, 162, 642, 2562, 10242};
  const int ac[10] = {32, 64, 128, 256, 512, 512, 256, 128, 64, 32};
  for (int i = 0; i < 10; ++i) {
    af[i] = alloc_f((size_t)an[i] * ac[i]);
    ah[i] = alloc_h((size_t)an[i] * ac[i]);
  }

  hipMemsetAsync(cnt, 0, (size_t)NT * 4, stream);
  k_fill<<<(ET + 255) / 256, 256, 0, stream>>>(ep, cnt, ell, ET);
  k_wfill<<<(NT * MAXD + 255) / 256, 256, 0, stream>>>(ep, cnt, ell, NT);
  k_cvt<<<(40962 * 4 + 255) / 256, 256, 0, stream>>>(x0f, x0h, 40962 * 4);
  {
    WPack P;
    int TOT = 0;
    for (int i = 0; i < 11; ++i) {
      P.src[i] = W[i];
      P.dst[i] = wp[i];
      P.cin[i] = LCI[i];
      P.cout[i] = LCO[i];
      P.tot[i] = 3 * LCI[i] * LCO[i];
      TOT += P.tot[i];
    }
    k_wpack<<<(TOT + 255) / 256, 256, 0, stream>>>(P, TOT);
  }

  auto plain = [](const float* hf, const bf16* hh, int Ch) {
    VSrc s{hf, hh, nullptr, nullptr, nullptr, 0, Ch, 0}; return s;
  };
  auto upsrc = [](const float* hf, const bf16* hh, const float* skf, const bf16* skh,
                  const int* u, int nprev, int Ch, int Cs) {
    VSrc s{hf, hh, skf, skh, u, nprev, Ch, Cs}; return s;
  };

  // big layer: flat fp32/bf16 X + paired prop_flat + paired prop2 + streaming combine
  auto big = [&](const float* Xf, const bf16* Xh, float* OUT, bf16* OUTh, int lvl, int n,
                 int Cin, int Cout, const float* Wq, const float* Bp, int smax) {
    int nb = ep.nbase[lvl];
    VSrc s = plain(Xf, Xh, Cin);
    int t4p = (n >> 1) * (Cin >> 2);
    k_prop_flat<<<(t4p + 255) / 256, 256, 0, stream>>>(Xh, t1f, t1h, cnt, ell, nb, n, Cin);
    k_prop2<<<(t4p + 255) / 256, 256, 0, stream>>>(Xf, t1h, t2f, cnt, ell, nb, n, Cin);
    int grid = ((Cout + 63) / 64) * ((n + 7) / 8);
    if (smax)
      k_combine<8, 1, 1, 0, 0><<<grid, 256, 0, stream>>>(s, t1f, t1h, t2f, (const float4*)Wq, Bp, cnt, ell, nb, n, Cin, Cout, 0, OUT, OUTh);
    else
      k_combine<8, 1, 0, 0, 0><<<grid, 256, 0, stream>>>(s, t1f, t1h, t2f, (const float4*)Wq, Bp, cnt, ell, nb, n, Cin, Cout, 1, OUT, OUTh);
  };

  // mid layer: virtual prop + gather-combine with W batching
#define MID(RS, CWv, s, OUT, OUTh, lvl, n, Cin, Cout, Wq, Bp)                                   \
  {                                                                                             \
    int nb = ep.nbase[lvl];                                                                     \
    int t2n = (n) * ((Cin) >> 1);                                                               \
    k_prop_v<<<(t2n + 255) / 256, 256, 0, stream>>>(s, t1f, t1h, cnt, ell, nb, n, Cin);         \
    int grid = (((Cout) + 63) / 64) * (((n) + (RS)-1) / (RS));                                  \
    k_combine<RS, CWv, 0, 1, 1><<<grid, 256, 0, stream>>>(s, t1f, t1h, nullptr, (const float4*)Wq, \
                                                          Bp, cnt, ell, nb, n, Cin, Cout, 1, OUT, OUTh); \
  }

  // ---- L1: n=40962, 4->32 ----
  big(x0f, x0h, af[0], ah[0], 5, 40962, 4, 32, wp[0], Bb[0], 0);
  // ---- L2: n=10242, 32->64 ----
  big(af[0], ah[0], af[1], ah[1], 4, 10242, 32, 64, wp[1], Bb[1], 0);
  // ---- mid encoder ----
  MID(4, 1, plain(af[1], ah[1], 64), af[2], ah[2], 3, 2562, 64, 128, wp[2], Bb[2]);
  MID(2, 2, plain(af[2], ah[2], 128), af[3], ah[3], 2, 642, 128, 256, wp[3], Bb[3]);
  MID(1, 4, plain(af[3], ah[3], 256), af[4], ah[4], 1, 162, 256, 512, wp[4], Bb[4]);
  MID(1, 4, plain(af[4], ah[4], 512), af[5], ah[5], 0, 42, 512, 512, wp[5], Bb[5]);
  // ---- mid decoder ----
  MID(1, 4, upsrc(af[5], ah[5], af[3], ah[3], up[0], 42, 512, 256), af[6], ah[6], 1, 162, 768, 256, wp[6], Bb[6]);
  MID(2, 4, upsrc(af[6], ah[6], af[2], ah[2], up[1], 162, 256, 128), af[7], ah[7], 2, 642, 384, 128, wp[7], Bb[7]);
  MID(2, 4, upsrc(af[7], ah[7], af[1], ah[1], up[2], 642, 128, 64), af[8], ah[8], 3, 2562, 192, 64, wp[8], Bb[8]);
  // ---- L10: n=10242, [64|32]->32 ----
  {
    VSrc s = upsrc(af[8], ah[8], af[0], ah[0], up[3], 2562, 64, 32);
    k_xmat2<<<(10242 * 48 + 255) / 256, 256, 0, stream>>>(s, xf, xh, 10242, 96);
    big(xf, xh, af[9], ah[9], 4, 10242, 96, 32, wp[9], Bb[9], 0);
  }
  // ---- L11: n=40962, [32|4]->37 + softmax ----
  {
    VSrc s = upsrc(af[9], ah[9], x0f, x0h, up[4], 10242, 32, 4);
    k_xmat2<<<(40962 * 18 + 255) / 256, 256, 0, stream>>>(s, xf, xh, 40962, 36);
    big(xf, xh, (float*)d_out, nullptr, 5, 40962, 36, 37, wp[10], Bb[10], 1);
  }
}

// Round 14
// 521.319 us; speedup vs baseline: 1.3469x; 1.0133x over previous
//
#include <hip/hip_runtime.h>
#include <hip/hip_bf16.h>

#define MAXD 32
typedef __hip_bfloat16 bf16;

__device__ __forceinline__ float bf2f(bf16 v) { return __bfloat162float(v); }
__device__ __forceinline__ float2 ldbf2(const bf16* p) {
  unsigned u = *(const unsigned*)p;
  return make_float2(__uint_as_float(u << 16), __uint_as_float(u & 0xffff0000u));
}
__device__ __forceinline__ float2 unpk(unsigned u) {
  return make_float2(__uint_as_float(u << 16), __uint_as_float(u & 0xffff0000u));
}
__device__ __forceinline__ unsigned pk2(float x, float y) {
  bf16 bx = __float2bfloat16(x), by = __float2bfloat16(y);
  unsigned short ux, uy;
  __builtin_memcpy(&ux, &bx, 2);
  __builtin_memcpy(&uy, &by, 2);
  return (unsigned)ux | ((unsigned)uy << 16);
}

struct EdgeParams {
  const int* e[6];
  int E[6];
  int ebase[6];
  int nbase[6];
};

struct VSrc {
  const float* hf; const bf16* hh;
  const float* skf; const bf16* skh;
  const int* up;
  int nprev, Ch, Cs;
};

__device__ __forceinline__ float vloadf(const VSrc& s, int i, int c) {
  if (s.up) {
    if (c >= s.Ch) return s.skf[(long)i * s.Cs + (c - s.Ch)];
    if (i >= s.nprev) {
      int j = i - s.nprev;
      int u0 = s.up[2 * j], u1 = s.up[2 * j + 1];
      return 0.5f * (s.hf[(long)u0 * s.Ch + c] + s.hf[(long)u1 * s.Ch + c]);
    }
    return s.hf[(long)i * s.Ch + c];
  }
  return s.hf[(long)i * s.Ch + c];
}

__device__ __forceinline__ float2 vloadh2(const VSrc& s, int i, int c2) {
  int c = 2 * c2;
  if (s.up) {
    if (c >= s.Ch) return ldbf2(s.skh + (long)i * s.Cs + (c - s.Ch));
    if (i >= s.nprev) {
      int j = i - s.nprev;
      int u0 = s.up[2 * j], u1 = s.up[2 * j + 1];
      float2 a = ldbf2(s.hh + (long)u0 * s.Ch + c);
      float2 b = ldbf2(s.hh + (long)u1 * s.Ch + c);
      return make_float2(0.5f * (a.x + b.x), 0.5f * (a.y + b.y));
    }
    return ldbf2(s.hh + (long)i * s.Ch + c);
  }
  return ldbf2(s.hh + (long)i * s.Ch + c);
}

__device__ __forceinline__ float2 vloadf2(const VSrc& s, int i, int c) {
  return make_float2(vloadf(s, i, c), vloadf(s, i, c + 1));
}

// ---------------- setup kernels ----------------
__global__ void k_fill(EdgeParams p, int* __restrict__ cnt, int2* __restrict__ ell, int ET) {
  for (int idx = blockIdx.x * blockDim.x + threadIdx.x; idx < ET; idx += gridDim.x * blockDim.x) {
    int l;
    if (idx < p.ebase[1]) l = 0;
    else if (idx < p.ebase[2]) l = 1;
    else if (idx < p.ebase[3]) l = 2;
    else if (idx < p.ebase[4]) l = 3;
    else if (idx < p.ebase[5]) l = 4;
    else l = 5;
    int e = idx - p.ebase[l];
    const int* epp = p.e[l];
    int row = epp[e];
    int col = epp[p.E[l] + e];
    int g = p.nbase[l] + row;
    int slot = atomicAdd(&cnt[g], 1);
    if (slot < MAXD) ell[g * MAXD + slot].x = col;
  }
}

__global__ void k_wfill(EdgeParams p, const int* __restrict__ cnt, int2* __restrict__ ell, int NT) {
  int total = NT * MAXD;
  for (int idx = blockIdx.x * blockDim.x + threadIdx.x; idx < total; idx += gridDim.x * blockDim.x) {
    int g = idx >> 5;
    int t = idx & (MAXD - 1);
    int dg = cnt[g];
    int d = dg < MAXD ? dg : MAXD;
    if (t < d) {
      int l;
      if (g < p.nbase[1]) l = 0;
      else if (g < p.nbase[2]) l = 1;
      else if (g < p.nbase[3]) l = 2;
      else if (g < p.nbase[4]) l = 3;
      else if (g < p.nbase[5]) l = 4;
      else l = 5;
      int c = ell[idx].x;
      int dc = cnt[p.nbase[l] + c];
      float w = (dc > 0) ? -(rsqrtf((float)dg) * rsqrtf((float)dc)) : 0.0f;
      ell[idx].y = __float_as_int(w);
    }
  }
}

// Repack W[3][Cin][Cout] -> Wp[3][Cin/4][Cout][4] for all 11 layers + x0 fp32->bf16.
struct WPack {
  const float* src[11];
  float* dst[11];
  int cin[11], cout[11], tot[11];
  const float* x0;
  bf16* x0h;
  int nx0;
};
__global__ void k_wpack(WPack P, int TOT) {
  int TALL = TOT + P.nx0;
  for (int idx = blockIdx.x * blockDim.x + threadIdx.x; idx < TALL; idx += gridDim.x * blockDim.x) {
    if (idx >= TOT) {
      int j = idx - TOT;
      P.x0h[j] = __float2bfloat16(P.x0[j]);
      continue;
    }
    int l = 0, off = idx;
    while (off >= P.tot[l]) { off -= P.tot[l]; ++l; }
    int cout = P.cout[l];
    int cinco = P.cin[l] * cout;
    int t = off / cinco;
    int rem = off - t * cinco;
    int k = rem / cout;
    int o = rem - k * cout;
    P.dst[l][((t * (P.cin[l] >> 2) + (k >> 2)) * cout + o) * 4 + (k & 3)] = P.src[l][off];
  }
}

// Materialize virtual upcat source into fp32 AND bf16 flat arrays.
__global__ void k_xmat2(VSrc src, float* __restrict__ Xf, bf16* __restrict__ Xh, int n, int Ctot) {
  int C2 = Ctot >> 1;
  int total = n * C2;
  for (int idx = blockIdx.x * blockDim.x + threadIdx.x; idx < total; idx += gridDim.x * blockDim.x) {
    int i = idx / C2;
    int c2 = idx - i * C2;
    float2 v = vloadf2(src, i, 2 * c2);
    long o = (long)i * Ctot + 2 * c2;
    *(float2*)(Xf + o) = v;
    *(unsigned*)(Xh + o) = pk2(v.x, v.y);
  }
}

// ---------------- big-layer gather kernels (2 rows/thread) ----------------
// Gather index clamped to 0 past the row's degree — slot 0 of a degree-0 row is
// uninitialized (0xAA poison -> faulting address otherwise).
__global__ void k_prop_flat(const bf16* __restrict__ Xh, float* __restrict__ T, bf16* __restrict__ Th,
                            const int* __restrict__ cnt, const int2* __restrict__ ell,
                            int nbase, int n, int C) {
  int C4 = C >> 2;
  int total = (n >> 1) * C4;  // n even for all big layers
  for (int idx = blockIdx.x * blockDim.x + threadIdx.x; idx < total; idx += gridDim.x * blockDim.x) {
    int ip = idx / C4;
    int c = (idx - ip * C4) << 2;
    int i0 = ip << 1, i1 = i0 + 1;
    int g0 = nbase + i0, g1 = nbase + i1;
    int d0 = cnt[g0]; if (d0 > MAXD) d0 = MAXD;
    int d1 = cnt[g1]; if (d1 > MAXD) d1 = MAXD;
    const int2* cols0 = ell + (long)g0 * MAXD;
    const int2* cols1 = ell + (long)g1 * MAXD;
    float a0 = 0.f, a1 = 0.f, a2 = 0.f, a3 = 0.f;
    float b0 = 0.f, b1 = 0.f, b2 = 0.f, b3 = 0.f;
    int dm = d0 > d1 ? d0 : d1;
    for (int t = 0; t < dm; t += 8) {
      int ciA[8], ciB[8]; float wA[8], wB[8];
#pragma unroll
      for (int j = 0; j < 8; ++j) {
        int tt = t + j;
        int2 eA = cols0[(tt < d0) ? tt : 0];
        int2 eB = cols1[(tt < d1) ? tt : 0];
        ciA[j] = (tt < d0) ? eA.x : 0;
        wA[j] = (tt < d0) ? __int_as_float(eA.y) : 0.f;
        ciB[j] = (tt < d1) ? eB.x : 0;
        wB[j] = (tt < d1) ? __int_as_float(eB.y) : 0.f;
      }
#pragma unroll
      for (int j = 0; j < 8; ++j) {
        uint2 rA = *(const uint2*)(Xh + (long)ciA[j] * C + c);
        uint2 rB = *(const uint2*)(Xh + (long)ciB[j] * C + c);
        float2 vA01 = unpk(rA.x), vA23 = unpk(rA.y);
        float2 vB01 = unpk(rB.x), vB23 = unpk(rB.y);
        a0 += wA[j] * vA01.x; a1 += wA[j] * vA01.y; a2 += wA[j] * vA23.x; a3 += wA[j] * vA23.y;
        b0 += wB[j] * vB01.x; b1 += wB[j] * vB01.y; b2 += wB[j] * vB23.x; b3 += wB[j] * vB23.y;
      }
    }
    long o0 = (long)i0 * C + c;
    long o1 = (long)i1 * C + c;
    *(float4*)(T + o0) = make_float4(a0, a1, a2, a3);
    *(float4*)(T + o1) = make_float4(b0, b1, b2, b3);
    uint2 pA; pA.x = pk2(a0, a1); pA.y = pk2(a2, a3);
    uint2 pB; pB.x = pk2(b0, b1); pB.y = pk2(b2, b3);
    *(uint2*)(Th + o0) = pA;
    *(uint2*)(Th + o1) = pB;
  }
}

// t2 = 2*A~t1 - x, x from FLAT fp32 X; 2 rows/thread; writes bf16 t2 only.
__global__ void k_prop2(const float* __restrict__ Xf, const bf16* __restrict__ T1h,
                        bf16* __restrict__ T2h,
                        const int* __restrict__ cnt, const int2* __restrict__ ell,
                        int nbase, int n, int C) {
  int C4 = C >> 2;
  int total = (n >> 1) * C4;
  for (int idx = blockIdx.x * blockDim.x + threadIdx.x; idx < total; idx += gridDim.x * blockDim.x) {
    int ip = idx / C4;
    int c = (idx - ip * C4) << 2;
    int i0 = ip << 1, i1 = i0 + 1;
    int g0 = nbase + i0, g1 = nbase + i1;
    int d0 = cnt[g0]; if (d0 > MAXD) d0 = MAXD;
    int d1 = cnt[g1]; if (d1 > MAXD) d1 = MAXD;
    const int2* cols0 = ell + (long)g0 * MAXD;
    const int2* cols1 = ell + (long)g1 * MAXD;
    float a0 = 0.f, a1 = 0.f, a2 = 0.f, a3 = 0.f;
    float b0 = 0.f, b1 = 0.f, b2 = 0.f, b3 = 0.f;
    int dm = d0 > d1 ? d0 : d1;
    for (int t = 0; t < dm; t += 8) {
      int ciA[8], ciB[8]; float wA[8], wB[8];
#pragma unroll
      for (int j = 0; j < 8; ++j) {
        int tt = t + j;
        int2 eA = cols0[(tt < d0) ? tt : 0];
        int2 eB = cols1[(tt < d1) ? tt : 0];
        ciA[j] = (tt < d0) ? eA.x : 0;
        wA[j] = (tt < d0) ? __int_as_float(eA.y) : 0.f;
        ciB[j] = (tt < d1) ? eB.x : 0;
        wB[j] = (tt < d1) ? __int_as_float(eB.y) : 0.f;
      }
#pragma unroll
      for (int j = 0; j < 8; ++j) {
        uint2 rA = *(const uint2*)(T1h + (long)ciA[j] * C + c);
        uint2 rB = *(const uint2*)(T1h + (long)ciB[j] * C + c);
        float2 vA01 = unpk(rA.x), vA23 = unpk(rA.y);
        float2 vB01 = unpk(rB.x), vB23 = unpk(rB.y);
        a0 += wA[j] * vA01.x; a1 += wA[j] * vA01.y; a2 += wA[j] * vA23.x; a3 += wA[j] * vA23.y;
        b0 += wB[j] * vB01.x; b1 += wB[j] * vB01.y; b2 += wB[j] * vB23.x; b3 += wB[j] * vB23.y;
      }
    }
    long o0 = (long)i0 * C + c;
    long o1 = (long)i1 * C + c;
    float4 x0 = *(const float4*)(Xf + o0);
    float4 x1 = *(const float4*)(Xf + o1);
    uint2 pA; pA.x = pk2(2.f * a0 - x0.x, 2.f * a1 - x0.y); pA.y = pk2(2.f * a2 - x0.z, 2.f * a3 - x0.w);
    uint2 pB; pB.x = pk2(2.f * b0 - x1.x, 2.f * b1 - x1.y); pB.y = pk2(2.f * b2 - x1.z, 2.f * b3 - x1.w);
    *(uint2*)(T2h + o0) = pA;
    *(uint2*)(T2h + o1) = pB;
  }
}

// mid-layer t1 gather from virtual source; pair of channels/thread.
__global__ void k_prop_v(VSrc src, float* __restrict__ T, bf16* __restrict__ Th,
                         const int* __restrict__ cnt, const int2* __restrict__ ell,
                         int nbase, int n, int C) {
  int C2 = C >> 1;
  int total = n * C2;
  for (int idx = blockIdx.x * blockDim.x + threadIdx.x; idx < total; idx += gridDim.x * blockDim.x) {
    int i = idx / C2;
    int c2 = idx - i * C2;
    int g = nbase + i;
    int d = cnt[g]; if (d > MAXD) d = MAXD;
    const int2* cols = ell + (long)g * MAXD;
    float ax = 0.f, ay = 0.f;
    for (int t = 0; t < d; t += 8) {
      int ci[8]; float wj[8];
#pragma unroll
      for (int j = 0; j < 8; ++j) {
        int tt = t + j;
        int2 e = cols[(tt < d) ? tt : 0];
        ci[j] = e.x;
        wj[j] = (tt < d) ? __int_as_float(e.y) : 0.f;
      }
#pragma unroll
      for (int j = 0; j < 8; ++j) {
        float2 v = vloadh2(src, ci[j], c2);
        ax += wj[j] * v.x;
        ay += wj[j] * v.y;
      }
    }
    long o = (long)i * C + 2 * c2;
    ((float2*)T)[o >> 1] = make_float2(ax, ay);
    *(unsigned*)(Th + o) = pk2(ax, ay);
  }
}

// ---------------- big-layer combine: bf16 X + fp32 t1 + bf16 t2 streams ----------------
template <int SMAX>
__global__ __launch_bounds__(256) void k_combine_big(
    const bf16* __restrict__ Xh, const float* __restrict__ T1, const bf16* __restrict__ T2h,
    const float4* __restrict__ Wp, const float* __restrict__ B,
    int n, int Cin, int Cout,
    float* __restrict__ OUT, bf16* __restrict__ OUTh) {
  constexpr int RPW = 2;  // ROWS=8, 4 row-groups
  __shared__ __align__(16) float sx[4][RPW][64];
  __shared__ __align__(16) float st1[4][RPW][64];
  __shared__ __align__(16) float st2[4][RPW][64];

  int tid = threadIdx.x;
  int w = tid >> 6;
  int lane = tid & 63;

  int colTiles = (Cout + 63) >> 6;
  int ct = blockIdx.x % colTiles;
  int rt = blockIdx.x / colTiles;
  int r0 = rt * 8 + w * RPW;
  int o = ct * 64 + lane;
  int oc = (o < Cout) ? o : (Cout - 1);
  int nch = (Cin + 63) >> 6;
  int KQ = Cin >> 2;

  float acc[RPW];
#pragma unroll
  for (int r = 0; r < RPW; ++r) acc[r] = 0.f;

  for (int c = 0; c < nch; ++c) {
    int k0 = c * 64;
    int kw = (Cin - k0 < 64) ? (Cin - k0) : 64;
    int k = k0 + lane;
    bool kv = lane < kw;

#pragma unroll
    for (int rr = 0; rr < RPW; ++rr) {
      int i = r0 + rr;
      bool iv = i < n;
      float xv = 0.f, tv = 0.f, t2v = 0.f;
      if (kv && iv) {
        long off = (long)i * Cin + k;
        xv = bf2f(Xh[off]);
        tv = T1[off];
        t2v = bf2f(T2h[off]);
      }
      sx[w][rr][lane] = xv;
      st1[w][rr][lane] = tv;
      st2[w][rr][lane] = t2v;
    }
    __syncthreads();

    int kw4 = kw >> 2;
    for (int q = 0; q < kw4; ++q) {
      int kq = (k0 >> 2) + q;
      float4 w0 = Wp[(0 * KQ + kq) * Cout + oc];
      float4 w1 = Wp[(1 * KQ + kq) * Cout + oc];
      float4 w2 = Wp[(2 * KQ + kq) * Cout + oc];
#pragma unroll
      for (int rr = 0; rr < RPW; ++rr) {
        float4 xs = ((const float4*)sx[w][rr])[q];
        float4 t1s = ((const float4*)st1[w][rr])[q];
        float4 t2s = ((const float4*)st2[w][rr])[q];
        acc[rr] += w0.x * xs.x + w0.y * xs.y + w0.z * xs.z + w0.w * xs.w;
        acc[rr] += w1.x * t1s.x + w1.y * t1s.y + w1.z * t1s.z + w1.w * t1s.w;
        acc[rr] += w2.x * t2s.x + w2.y * t2s.y + w2.z * t2s.z + w2.w * t2s.w;
      }
    }
    __syncthreads();
  }

  if constexpr (SMAX) {
    float bb = (o < Cout) ? B[o] : 0.f;
#pragma unroll
    for (int rr = 0; rr < RPW; ++rr) {
      int i = r0 + rr;
      if (i < n) {
        float v = (o < Cout) ? (acc[rr] + bb) : -1e30f;
        float m = v;
        for (int s = 32; s > 0; s >>= 1) m = fmaxf(m, __shfl_xor(m, s));
        float e = (o < Cout) ? __expf(v - m) : 0.f;
        float sum = e;
        for (int s = 32; s > 0; s >>= 1) sum += __shfl_xor(sum, s);
        if (o < Cout) OUT[(long)i * Cout + o] = e / sum;
      }
    }
  } else {
    if (o < Cout) {
      float bb = B[oc];
#pragma unroll
      for (int rr = 0; rr < RPW; ++rr) {
        int i = r0 + rr;
        if (i < n) {
          float v = fmaxf(acc[rr] + bb, 0.f);
          long off = (long)i * Cout + o;
          OUT[off] = v;
          OUTh[off] = __float2bfloat16(v);
        }
      }
    }
  }
}

// ---------------- mid-layer combine: [X|t1|t2] @ Wp + b (+relu), t2 gathered ----------------
template <int ROWS, int CW>
__global__ __launch_bounds__(256) void k_combine(
    VSrc src, const float* __restrict__ T1, const bf16* __restrict__ T1h,
    const float4* __restrict__ Wp, const float* __restrict__ B,
    const int* __restrict__ cnt, const int2* __restrict__ ell,
    int nbase, int n, int Cin, int Cout,
    float* __restrict__ OUT, bf16* __restrict__ OUTh) {
  constexpr int RW = 4 / CW;
  constexpr int RPW = (ROWS * CW) / 4;
  static_assert(RPW * RW == ROWS, "bad ROWS/CW combo");

  __shared__ __align__(16) float sx[4][RPW][64];
  __shared__ __align__(16) float st1[4][RPW][64];
  __shared__ __align__(16) float st2[4][RPW][64];

  int tid = threadIdx.x;
  int w = tid >> 6;
  int lane = tid & 63;
  int rg = w / CW;
  int cw = w % CW;

  int colTiles = (Cout + 63) >> 6;
  int ct = blockIdx.x % colTiles;
  int rt = blockIdx.x / colTiles;
  int r0 = rt * ROWS + rg * RPW;
  int o = ct * 64 + lane;
  int oc = (o < Cout) ? o : (Cout - 1);
  int nch = (Cin + 63) >> 6;
  int KQ = Cin >> 2;

  float acc[RPW];
#pragma unroll
  for (int r = 0; r < RPW; ++r) acc[r] = 0.f;

  for (int cg = 0; cg < nch; cg += CW) {
    int c = cg + cw;
    bool act = c < nch;
    int k0 = c * 64;
    int kw = act ? ((Cin - k0 < 64) ? (Cin - k0) : 64) : 0;
    int k = k0 + lane;
    bool kv = act && (lane < kw);

#pragma unroll
    for (int rr = 0; rr < RPW; ++rr) {
      int i = r0 + rr;
      bool iv = i < n;
      float xv = 0.f, tv = 0.f, t2v = 0.f;
      if (kv && iv) {
        xv = vloadf(src, i, k);
        tv = T1[(long)i * Cin + k];
        int g = nbase + i;
        int d = cnt[g]; if (d > MAXD) d = MAXD;
        const int2* cols = ell + (long)g * MAXD;
        float a2 = 0.f;
        for (int t = 0; t < d; t += 8) {
          int ci[8]; float wj[8];
#pragma unroll
          for (int j = 0; j < 8; ++j) {
            int tt = t + j;
            int2 e = cols[(tt < d) ? tt : 0];
            ci[j] = e.x;
            wj[j] = (tt < d) ? __int_as_float(e.y) : 0.f;
          }
#pragma unroll
          for (int j = 0; j < 8; ++j)
            a2 += wj[j] * bf2f(T1h[(long)ci[j] * Cin + k]);
        }
        t2v = 2.f * a2 - xv;
      }
      sx[w][rr][lane] = xv;
      st1[w][rr][lane] = tv;
      st2[w][rr][lane] = t2v;
    }
    __syncthreads();

    int kw4 = kw >> 2;
    int kqb = k0 >> 2;
    int qb = 0;
    // 8-deep W preload (big mid W is L2-cold)
    for (; qb + 8 <= kw4; qb += 8) {
      float4 wb0[8], wb1[8], wb2[8];
#pragma unroll
      for (int q = 0; q < 8; ++q) {
        int kq = kqb + qb + q;
        wb0[q] = Wp[(0 * KQ + kq) * Cout + oc];
        wb1[q] = Wp[(1 * KQ + kq) * Cout + oc];
        wb2[q] = Wp[(2 * KQ + kq) * Cout + oc];
      }
#pragma unroll
      for (int q = 0; q < 8; ++q) {
#pragma unroll
        for (int rr = 0; rr < RPW; ++rr) {
          float4 xs = ((const float4*)sx[w][rr])[qb + q];
          float4 t1s = ((const float4*)st1[w][rr])[qb + q];
          float4 t2s = ((const float4*)st2[w][rr])[qb + q];
          acc[rr] += wb0[q].x * xs.x + wb0[q].y * xs.y + wb0[q].z * xs.z + wb0[q].w * xs.w;
          acc[rr] += wb1[q].x * t1s.x + wb1[q].y * t1s.y + wb1[q].z * t1s.z + wb1[q].w * t1s.w;
          acc[rr] += wb2[q].x * t2s.x + wb2[q].y * t2s.y + wb2[q].z * t2s.z + wb2[q].w * t2s.w;
        }
      }
    }
    for (int q = qb; q < kw4; ++q) {
      int kq = kqb + q;
      float4 w0 = Wp[(0 * KQ + kq) * Cout + oc];
      float4 w1 = Wp[(1 * KQ + kq) * Cout + oc];
      float4 w2 = Wp[(2 * KQ + kq) * Cout + oc];
#pragma unroll
      for (int rr = 0; rr < RPW; ++rr) {
        float4 xs = ((const float4*)sx[w][rr])[q];
        float4 t1s = ((const float4*)st1[w][rr])[q];
        float4 t2s = ((const float4*)st2[w][rr])[q];
        acc[rr] += w0.x * xs.x + w0.y * xs.y + w0.z * xs.z + w0.w * xs.w;
        acc[rr] += w1.x * t1s.x + w1.y * t1s.y + w1.z * t1s.z + w1.w * t1s.w;
        acc[rr] += w2.x * t2s.x + w2.y * t2s.y + w2.z * t2s.z + w2.w * t2s.w;
      }
    }
    __syncthreads();
  }

  if constexpr (CW == 1) {
    if (o < Cout) {
      float bb = B[oc];
#pragma unroll
      for (int rr = 0; rr < RPW; ++rr) {
        int i = r0 + rr;
        if (i < n) {
          float v = fmaxf(acc[rr] + bb, 0.f);
          long off = (long)i * Cout + o;
          OUT[off] = v;
          OUTh[off] = __float2bfloat16(v);
        }
      }
    }
  } else {
#pragma unroll
    for (int rr = 0; rr < RPW; ++rr) sx[w][rr][lane] = acc[rr];
    __syncthreads();
    if (cw == 0 && o < Cout) {
      float bb = B[oc];
#pragma unroll
      for (int rr = 0; rr < RPW; ++rr) {
        int i = r0 + rr;
        if (i < n) {
          float v = bb;
#pragma unroll
          for (int j = 0; j < CW; ++j) v += sx[rg * CW + j][rr][lane];
          v = fmaxf(v, 0.f);
          long off = (long)i * Cout + o;
          OUT[off] = v;
          OUTh[off] = __float2bfloat16(v);
        }
      }
    }
  }
}

// ---------------- launcher ----------------
extern "C" void kernel_launch(void* const* d_in, const int* in_sizes, int n_in,
                              void* d_out, int out_size, void* d_ws, size_t ws_size,
                              hipStream_t stream) {
  static const int NV[6] = {42, 162, 642, 2562, 10242, 40962};
  static const int NE[6] = {240, 960, 3840, 15360, 61440, 245760};
  const int NT = 54612;
  const int ET = 327600;

  EdgeParams ep;
  {
    int nb = 0, eb = 0;
    for (int l = 0; l < 6; ++l) {
      ep.e[l] = (const int*)d_in[1 + l];
      ep.E[l] = NE[l];
      ep.ebase[l] = eb;
      ep.nbase[l] = nb;
      eb += NE[l];
      nb += NV[l];
    }
  }
  const float* x0f = (const float*)d_in[0];
  const int* up[5];
  for (int i = 0; i < 5; ++i) up[i] = (const int*)d_in[7 + i];  // up2..up6
  const float *W[11], *Bb[11];
  for (int i = 0; i < 11; ++i) {
    W[i] = (const float*)d_in[12 + 2 * i];
    Bb[i] = (const float*)d_in[13 + 2 * i];
  }
  static const int LCI[11] = {4, 32, 64, 128, 256, 512, 768, 384, 192, 96, 36};
  static const int LCO[11] = {32, 64, 128, 256, 512, 512, 256, 128, 64, 32, 37};

  // ---- workspace carve (16B-aligned) ----
  char* p = (char*)d_ws;
  auto alloc_b = [&](size_t bytes) { void* r = (void*)p; p += (bytes + 15) & ~size_t(15); return r; };
  auto alloc_i = [&](size_t ne) { return (int*)alloc_b(ne * 4); };
  auto alloc_f = [&](size_t ne) { return (float*)alloc_b(ne * 4); };
  auto alloc_h = [&](size_t ne) { return (bf16*)alloc_b(ne * 2); };
  int* cnt = alloc_i(NT);
  int2* ell = (int2*)alloc_b((size_t)NT * MAXD * 8);
  float* t1f = alloc_f((size_t)40962 * 36);
  bf16* t1h = alloc_h((size_t)40962 * 36);
  bf16* t2h = alloc_h((size_t)40962 * 36);
  bf16* x0h = alloc_h((size_t)40962 * 4);
  float* xf = alloc_f((size_t)40962 * 36);  // L10/L11 materialized fp32 X
  bf16* xh = alloc_h((size_t)40962 * 36);   // and bf16 shadow
  float* wp[11];
  for (int i = 0; i < 11; ++i) wp[i] = alloc_f((size_t)3 * LCI[i] * LCO[i]);
  float *af[10]; bf16 *ah[10];
  const int an[10] = {40962, 10242, 2562, 642, 162, 42, 162, 642, 2562, 10242};
  const int ac[10] = {32, 64, 128, 256, 512, 512, 256, 128, 64, 32};
  for (int i = 0; i < 10; ++i) {
    af[i] = alloc_f((size_t)an[i] * ac[i]);
    ah[i] = alloc_h((size_t)an[i] * ac[i]);
  }

  hipMemsetAsync(cnt, 0, (size_t)NT * 4, stream);
  k_fill<<<(ET + 255) / 256, 256, 0, stream>>>(ep, cnt, ell, ET);
  k_wfill<<<(NT * MAXD + 255) / 256, 256, 0, stream>>>(ep, cnt, ell, NT);
  {
    WPack P;
    int TOT = 0;
    for (int i = 0; i < 11; ++i) {
      P.src[i] = W[i];
      P.dst[i] = wp[i];
      P.cin[i] = LCI[i];
      P.cout[i] = LCO[i];
      P.tot[i] = 3 * LCI[i] * LCO[i];
      TOT += P.tot[i];
    }
    P.x0 = x0f; P.x0h = x0h; P.nx0 = 40962 * 4;
    k_wpack<<<(TOT + P.nx0 + 255) / 256, 256, 0, stream>>>(P, TOT);
  }

  auto plain = [](const float* hf, const bf16* hh, int Ch) {
    VSrc s{hf, hh, nullptr, nullptr, nullptr, 0, Ch, 0}; return s;
  };
  auto upsrc = [](const float* hf, const bf16* hh, const float* skf, const bf16* skh,
                  const int* u, int nprev, int Ch, int Cs) {
    VSrc s{hf, hh, skf, skh, u, nprev, Ch, Cs}; return s;
  };

  // big layer: paired prop_flat + paired prop2(bf16 out) + bf16-stream combine
  auto big = [&](const float* Xf, const bf16* Xh, float* OUT, bf16* OUTh, int lvl, int n,
                 int Cin, int Cout, const float* Wq, const float* Bp, int smax) {
    int nb = ep.nbase[lvl];
    int t4p = (n >> 1) * (Cin >> 2);
    k_prop_flat<<<(t4p + 255) / 256, 256, 0, stream>>>(Xh, t1f, t1h, cnt, ell, nb, n, Cin);
    k_prop2<<<(t4p + 255) / 256, 256, 0, stream>>>(Xf, t1h, t2h, cnt, ell, nb, n, Cin);
    int grid = ((Cout + 63) / 64) * ((n + 7) / 8);
    if (smax)
      k_combine_big<1><<<grid, 256, 0, stream>>>(Xh, t1f, t2h, (const float4*)Wq, Bp, n, Cin, Cout, OUT, OUTh);
    else
      k_combine_big<0><<<grid, 256, 0, stream>>>(Xh, t1f, t2h, (const float4*)Wq, Bp, n, Cin, Cout, OUT, OUTh);
  };

  // mid layer: virtual prop + gather-combine with W batching
#define MID(RS, CWv, s, OUT, OUTh, lvl, n, Cin, Cout, Wq, Bp)                                   \
  {                                                                                             \
    int nb = ep.nbase[lvl];                                                                     \
    int t2n = (n) * ((Cin) >> 1);                                                               \
    k_prop_v<<<(t2n + 255) / 256, 256, 0, stream>>>(s, t1f, t1h, cnt, ell, nb, n, Cin);         \
    int grid = (((Cout) + 63) / 64) * (((n) + (RS)-1) / (RS));                                  \
    k_combine<RS, CWv><<<grid, 256, 0, stream>>>(s, t1f, t1h, (const float4*)Wq,                \
                                                 Bp, cnt, ell, nb, n, Cin, Cout, OUT, OUTh);    \
  }

  // ---- L1: n=40962, 4->32 ----
  big(x0f, x0h, af[0], ah[0], 5, 40962, 4, 32, wp[0], Bb[0], 0);
  // ---- L2: n=10242, 32->64 ----
  big(af[0], ah[0], af[1], ah[1], 4, 10242, 32, 64, wp[1], Bb[1], 0);
  // ---- mid encoder ----
  MID(4, 1, plain(af[1], ah[1], 64), af[2], ah[2], 3, 2562, 64, 128, wp[2], Bb[2]);
  MID(2, 2, plain(af[2], ah[2], 128), af[3], ah[3], 2, 642, 128, 256, wp[3], Bb[3]);
  MID(1, 4, plain(af[3], ah[3], 256), af[4], ah[4], 1, 162, 256, 512, wp[4], Bb[4]);
  MID(1, 4, plain(af[4], ah[4], 512), af[5], ah[5], 0, 42, 512, 512, wp[5], Bb[5]);
  // ---- mid decoder ----
  MID(1, 4, upsrc(af[5], ah[5], af[3], ah[3], up[0], 42, 512, 256), af[6], ah[6], 1, 162, 768, 256, wp[6], Bb[6]);
  MID(2, 4, upsrc(af[6], ah[6], af[2], ah[2], up[1], 162, 256, 128), af[7], ah[7], 2, 642, 384, 128, wp[7], Bb[7]);
  MID(2, 4, upsrc(af[7], ah[7], af[1], ah[1], up[2], 642, 128, 64), af[8], ah[8], 3, 2562, 192, 64, wp[8], Bb[8]);
  // ---- L10: n=10242, [64|32]->32 ----
  {
    VSrc s = upsrc(af[8], ah[8], af[0], ah[0], up[3], 2562, 64, 32);
    k_xmat2<<<(10242 * 48 + 255) / 256, 256, 0, stream>>>(s, xf, xh, 10242, 96);
    big(xf, xh, af[9], ah[9], 4, 10242, 96, 32, wp[9], Bb[9], 0);
  }
  // ---- L11: n=40962, [32|4]->37 + softmax ----
  {
    VSrc s = upsrc(af[9], ah[9], x0f, x0h, up[4], 10242, 32, 4);
    k_xmat2<<<(40962 * 18 + 255) / 256, 256, 0, stream>>>(s, xf, xh, 40962, 36);
    big(xf, xh, (float*)d_out, nullptr, 5, 40962, 36, 37, wp[10], Bb[10], 1);
  }
}

// Round 15
// 520.438 us; speedup vs baseline: 1.3492x; 1.0017x over previous
//
#include <hip/hip_runtime.h>
#include <hip/hip_bf16.h>

#define MAXD 32
typedef __hip_bfloat16 bf16;

__device__ __forceinline__ float bf2f(bf16 v) { return __bfloat162float(v); }
__device__ __forceinline__ float2 ldbf2(const bf16* p) {
  unsigned u = *(const unsigned*)p;
  return make_float2(__uint_as_float(u << 16), __uint_as_float(u & 0xffff0000u));
}
__device__ __forceinline__ float2 unpk(unsigned u) {
  return make_float2(__uint_as_float(u << 16), __uint_as_float(u & 0xffff0000u));
}
__device__ __forceinline__ unsigned pk2(float x, float y) {
  bf16 bx = __float2bfloat16(x), by = __float2bfloat16(y);
  unsigned short ux, uy;
  __builtin_memcpy(&ux, &bx, 2);
  __builtin_memcpy(&uy, &by, 2);
  return (unsigned)ux | ((unsigned)uy << 16);
}

struct EdgeParams {
  const int* e[6];
  int E[6];
  int ebase[6];
  int nbase[6];
};

struct VSrc {
  const float* hf; const bf16* hh;
  const float* skf; const bf16* skh;
  const int* up;
  int nprev, Ch, Cs;
};

__device__ __forceinline__ float vloadf(const VSrc& s, int i, int c) {
  if (s.up) {
    if (c >= s.Ch) return s.skf[(long)i * s.Cs + (c - s.Ch)];
    if (i >= s.nprev) {
      int j = i - s.nprev;
      int u0 = s.up[2 * j], u1 = s.up[2 * j + 1];
      return 0.5f * (s.hf[(long)u0 * s.Ch + c] + s.hf[(long)u1 * s.Ch + c]);
    }
    return s.hf[(long)i * s.Ch + c];
  }
  return s.hf[(long)i * s.Ch + c];
}

__device__ __forceinline__ float2 vloadh2(const VSrc& s, int i, int c2) {
  int c = 2 * c2;
  if (s.up) {
    if (c >= s.Ch) return ldbf2(s.skh + (long)i * s.Cs + (c - s.Ch));
    if (i >= s.nprev) {
      int j = i - s.nprev;
      int u0 = s.up[2 * j], u1 = s.up[2 * j + 1];
      float2 a = ldbf2(s.hh + (long)u0 * s.Ch + c);
      float2 b = ldbf2(s.hh + (long)u1 * s.Ch + c);
      return make_float2(0.5f * (a.x + b.x), 0.5f * (a.y + b.y));
    }
    return ldbf2(s.hh + (long)i * s.Ch + c);
  }
  return ldbf2(s.hh + (long)i * s.Ch + c);
}

__device__ __forceinline__ float2 vloadf2(const VSrc& s, int i, int c) {
  return make_float2(vloadf(s, i, c), vloadf(s, i, c + 1));
}

// ---------------- setup kernels ----------------
__global__ void k_fill(EdgeParams p, int* __restrict__ cnt, int2* __restrict__ ell, int ET) {
  for (int idx = blockIdx.x * blockDim.x + threadIdx.x; idx < ET; idx += gridDim.x * blockDim.x) {
    int l;
    if (idx < p.ebase[1]) l = 0;
    else if (idx < p.ebase[2]) l = 1;
    else if (idx < p.ebase[3]) l = 2;
    else if (idx < p.ebase[4]) l = 3;
    else if (idx < p.ebase[5]) l = 4;
    else l = 5;
    int e = idx - p.ebase[l];
    const int* epp = p.e[l];
    int row = epp[e];
    int col = epp[p.E[l] + e];
    int g = p.nbase[l] + row;
    int slot = atomicAdd(&cnt[g], 1);
    if (slot < MAXD) ell[g * MAXD + slot].x = col;
  }
}

__global__ void k_wfill(EdgeParams p, const int* __restrict__ cnt, int2* __restrict__ ell, int NT) {
  int total = NT * MAXD;
  for (int idx = blockIdx.x * blockDim.x + threadIdx.x; idx < total; idx += gridDim.x * blockDim.x) {
    int g = idx >> 5;
    int t = idx & (MAXD - 1);
    int dg = cnt[g];
    int d = dg < MAXD ? dg : MAXD;
    if (t < d) {
      int l;
      if (g < p.nbase[1]) l = 0;
      else if (g < p.nbase[2]) l = 1;
      else if (g < p.nbase[3]) l = 2;
      else if (g < p.nbase[4]) l = 3;
      else if (g < p.nbase[5]) l = 4;
      else l = 5;
      int c = ell[idx].x;
      int dc = cnt[p.nbase[l] + c];
      float w = (dc > 0) ? -(rsqrtf((float)dg) * rsqrtf((float)dc)) : 0.0f;
      ell[idx].y = __float_as_int(w);
    }
  }
}

// Repack W[3][Cin][Cout] -> Wp[3][Cin/4][Cout][4] for all 11 layers + x0 fp32->bf16.
struct WPack {
  const float* src[11];
  float* dst[11];
  int cin[11], cout[11], tot[11];
  const float* x0;
  bf16* x0h;
  int nx0;
};
__global__ void k_wpack(WPack P, int TOT) {
  int TALL = TOT + P.nx0;
  for (int idx = blockIdx.x * blockDim.x + threadIdx.x; idx < TALL; idx += gridDim.x * blockDim.x) {
    if (idx >= TOT) {
      int j = idx - TOT;
      P.x0h[j] = __float2bfloat16(P.x0[j]);
      continue;
    }
    int l = 0, off = idx;
    while (off >= P.tot[l]) { off -= P.tot[l]; ++l; }
    int cout = P.cout[l];
    int cinco = P.cin[l] * cout;
    int t = off / cinco;
    int rem = off - t * cinco;
    int k = rem / cout;
    int o = rem - k * cout;
    P.dst[l][((t * (P.cin[l] >> 2) + (k >> 2)) * cout + o) * 4 + (k & 3)] = P.src[l][off];
  }
}

// Materialize virtual upcat source into bf16 flat array.
__global__ void k_xmat(VSrc src, bf16* __restrict__ Xh, int n, int Ctot) {
  int C2 = Ctot >> 1;
  int total = n * C2;
  for (int idx = blockIdx.x * blockDim.x + threadIdx.x; idx < total; idx += gridDim.x * blockDim.x) {
    int i = idx / C2;
    int c2 = idx - i * C2;
    float2 v = vloadf2(src, i, 2 * c2);
    *(unsigned*)(Xh + (long)i * Ctot + 2 * c2) = pk2(v.x, v.y);
  }
}

// ---------------- big-layer gather kernels (2 rows/thread) ----------------
// Gather index clamped to 0 past the row's degree — slot 0 of a degree-0 row is
// uninitialized (0xAA poison -> faulting address otherwise).
__global__ void k_prop_flat(const bf16* __restrict__ Xh, bf16* __restrict__ Th,
                            const int* __restrict__ cnt, const int2* __restrict__ ell,
                            int nbase, int n, int C) {
  int C4 = C >> 2;
  int total = (n >> 1) * C4;  // n even for all big layers
  for (int idx = blockIdx.x * blockDim.x + threadIdx.x; idx < total; idx += gridDim.x * blockDim.x) {
    int ip = idx / C4;
    int c = (idx - ip * C4) << 2;
    int i0 = ip << 1, i1 = i0 + 1;
    int g0 = nbase + i0, g1 = nbase + i1;
    int d0 = cnt[g0]; if (d0 > MAXD) d0 = MAXD;
    int d1 = cnt[g1]; if (d1 > MAXD) d1 = MAXD;
    const int2* cols0 = ell + (long)g0 * MAXD;
    const int2* cols1 = ell + (long)g1 * MAXD;
    float a0 = 0.f, a1 = 0.f, a2 = 0.f, a3 = 0.f;
    float b0 = 0.f, b1 = 0.f, b2 = 0.f, b3 = 0.f;
    int dm = d0 > d1 ? d0 : d1;
    for (int t = 0; t < dm; t += 8) {
      int ciA[8], ciB[8]; float wA[8], wB[8];
#pragma unroll
      for (int j = 0; j < 8; ++j) {
        int tt = t + j;
        int2 eA = cols0[(tt < d0) ? tt : 0];
        int2 eB = cols1[(tt < d1) ? tt : 0];
        ciA[j] = (tt < d0) ? eA.x : 0;
        wA[j] = (tt < d0) ? __int_as_float(eA.y) : 0.f;
        ciB[j] = (tt < d1) ? eB.x : 0;
        wB[j] = (tt < d1) ? __int_as_float(eB.y) : 0.f;
      }
#pragma unroll
      for (int j = 0; j < 8; ++j) {
        uint2 rA = *(const uint2*)(Xh + (long)ciA[j] * C + c);
        uint2 rB = *(const uint2*)(Xh + (long)ciB[j] * C + c);
        float2 vA01 = unpk(rA.x), vA23 = unpk(rA.y);
        float2 vB01 = unpk(rB.x), vB23 = unpk(rB.y);
        a0 += wA[j] * vA01.x; a1 += wA[j] * vA01.y; a2 += wA[j] * vA23.x; a3 += wA[j] * vA23.y;
        b0 += wB[j] * vB01.x; b1 += wB[j] * vB01.y; b2 += wB[j] * vB23.x; b3 += wB[j] * vB23.y;
      }
    }
    long o0 = (long)i0 * C + c;
    long o1 = (long)i1 * C + c;
    uint2 pA; pA.x = pk2(a0, a1); pA.y = pk2(a2, a3);
    uint2 pB; pB.x = pk2(b0, b1); pB.y = pk2(b2, b3);
    *(uint2*)(Th + o0) = pA;
    *(uint2*)(Th + o1) = pB;
  }
}

// t2 = 2*A~t1 - x, x from bf16 flat X; 2 rows/thread; writes bf16 t2.
__global__ void k_prop2(const bf16* __restrict__ Xh, const bf16* __restrict__ T1h,
                        bf16* __restrict__ T2h,
                        const int* __restrict__ cnt, const int2* __restrict__ ell,
                        int nbase, int n, int C) {
  int C4 = C >> 2;
  int total = (n >> 1) * C4;
  for (int idx = blockIdx.x * blockDim.x + threadIdx.x; idx < total; idx += gridDim.x * blockDim.x) {
    int ip = idx / C4;
    int c = (idx - ip * C4) << 2;
    int i0 = ip << 1, i1 = i0 + 1;
    int g0 = nbase + i0, g1 = nbase + i1;
    int d0 = cnt[g0]; if (d0 > MAXD) d0 = MAXD;
    int d1 = cnt[g1]; if (d1 > MAXD) d1 = MAXD;
    const int2* cols0 = ell + (long)g0 * MAXD;
    const int2* cols1 = ell + (long)g1 * MAXD;
    float a0 = 0.f, a1 = 0.f, a2 = 0.f, a3 = 0.f;
    float b0 = 0.f, b1 = 0.f, b2 = 0.f, b3 = 0.f;
    int dm = d0 > d1 ? d0 : d1;
    for (int t = 0; t < dm; t += 8) {
      int ciA[8], ciB[8]; float wA[8], wB[8];
#pragma unroll
      for (int j = 0; j < 8; ++j) {
        int tt = t + j;
        int2 eA = cols0[(tt < d0) ? tt : 0];
        int2 eB = cols1[(tt < d1) ? tt : 0];
        ciA[j] = (tt < d0) ? eA.x : 0;
        wA[j] = (tt < d0) ? __int_as_float(eA.y) : 0.f;
        ciB[j] = (tt < d1) ? eB.x : 0;
        wB[j] = (tt < d1) ? __int_as_float(eB.y) : 0.f;
      }
#pragma unroll
      for (int j = 0; j < 8; ++j) {
        uint2 rA = *(const uint2*)(T1h + (long)ciA[j] * C + c);
        uint2 rB = *(const uint2*)(T1h + (long)ciB[j] * C + c);
        float2 vA01 = unpk(rA.x), vA23 = unpk(rA.y);
        float2 vB01 = unpk(rB.x), vB23 = unpk(rB.y);
        a0 += wA[j] * vA01.x; a1 += wA[j] * vA01.y; a2 += wA[j] * vA23.x; a3 += wA[j] * vA23.y;
        b0 += wB[j] * vB01.x; b1 += wB[j] * vB01.y; b2 += wB[j] * vB23.x; b3 += wB[j] * vB23.y;
      }
    }
    long o0 = (long)i0 * C + c;
    long o1 = (long)i1 * C + c;
    uint2 xr0 = *(const uint2*)(Xh + o0);
    uint2 xr1 = *(const uint2*)(Xh + o1);
    float2 x001 = unpk(xr0.x), x023 = unpk(xr0.y);
    float2 x101 = unpk(xr1.x), x123 = unpk(xr1.y);
    uint2 pA; pA.x = pk2(2.f * a0 - x001.x, 2.f * a1 - x001.y); pA.y = pk2(2.f * a2 - x023.x, 2.f * a3 - x023.y);
    uint2 pB; pB.x = pk2(2.f * b0 - x101.x, 2.f * b1 - x101.y); pB.y = pk2(2.f * b2 - x123.x, 2.f * b3 - x123.y);
    *(uint2*)(T2h + o0) = pA;
    *(uint2*)(T2h + o1) = pB;
  }
}

// mid-layer t1 gather from virtual source; pair of channels/thread.
__global__ void k_prop_v(VSrc src, float* __restrict__ T, bf16* __restrict__ Th,
                         const int* __restrict__ cnt, const int2* __restrict__ ell,
                         int nbase, int n, int C) {
  int C2 = C >> 1;
  int total = n * C2;
  for (int idx = blockIdx.x * blockDim.x + threadIdx.x; idx < total; idx += gridDim.x * blockDim.x) {
    int i = idx / C2;
    int c2 = idx - i * C2;
    int g = nbase + i;
    int d = cnt[g]; if (d > MAXD) d = MAXD;
    const int2* cols = ell + (long)g * MAXD;
    float ax = 0.f, ay = 0.f;
    for (int t = 0; t < d; t += 8) {
      int ci[8]; float wj[8];
#pragma unroll
      for (int j = 0; j < 8; ++j) {
        int tt = t + j;
        int2 e = cols[(tt < d) ? tt : 0];
        ci[j] = e.x;
        wj[j] = (tt < d) ? __int_as_float(e.y) : 0.f;
      }
#pragma unroll
      for (int j = 0; j < 8; ++j) {
        float2 v = vloadh2(src, ci[j], c2);
        ax += wj[j] * v.x;
        ay += wj[j] * v.y;
      }
    }
    long o = (long)i * C + 2 * c2;
    ((float2*)T)[o >> 1] = make_float2(ax, ay);
    *(unsigned*)(Th + o) = pk2(ax, ay);
  }
}

// ---------------- big-layer combine: all-bf16 X/t1/t2 streams ----------------
template <int SMAX>
__global__ __launch_bounds__(256) void k_combine_big(
    const bf16* __restrict__ Xh, const bf16* __restrict__ T1h, const bf16* __restrict__ T2h,
    const float4* __restrict__ Wp, const float* __restrict__ B,
    int n, int Cin, int Cout,
    float* __restrict__ OUT, bf16* __restrict__ OUTh) {
  constexpr int RPW = 2;  // ROWS=8, 4 row-groups
  __shared__ __align__(16) float sx[4][RPW][64];
  __shared__ __align__(16) float st1[4][RPW][64];
  __shared__ __align__(16) float st2[4][RPW][64];

  int tid = threadIdx.x;
  int w = tid >> 6;
  int lane = tid & 63;

  int colTiles = (Cout + 63) >> 6;
  int ct = blockIdx.x % colTiles;
  int rt = blockIdx.x / colTiles;
  int r0 = rt * 8 + w * RPW;
  int o = ct * 64 + lane;
  int oc = (o < Cout) ? o : (Cout - 1);
  int nch = (Cin + 63) >> 6;
  int KQ = Cin >> 2;

  float acc[RPW];
#pragma unroll
  for (int r = 0; r < RPW; ++r) acc[r] = 0.f;

  for (int c = 0; c < nch; ++c) {
    int k0 = c * 64;
    int kw = (Cin - k0 < 64) ? (Cin - k0) : 64;
    int k = k0 + lane;
    bool kv = lane < kw;

#pragma unroll
    for (int rr = 0; rr < RPW; ++rr) {
      int i = r0 + rr;
      bool iv = i < n;
      float xv = 0.f, tv = 0.f, t2v = 0.f;
      if (kv && iv) {
        long off = (long)i * Cin + k;
        xv = bf2f(Xh[off]);
        tv = bf2f(T1h[off]);
        t2v = bf2f(T2h[off]);
      }
      sx[w][rr][lane] = xv;
      st1[w][rr][lane] = tv;
      st2[w][rr][lane] = t2v;
    }
    __syncthreads();

    int kw4 = kw >> 2;
    for (int q = 0; q < kw4; ++q) {
      int kq = (k0 >> 2) + q;
      float4 w0 = Wp[(0 * KQ + kq) * Cout + oc];
      float4 w1 = Wp[(1 * KQ + kq) * Cout + oc];
      float4 w2 = Wp[(2 * KQ + kq) * Cout + oc];
#pragma unroll
      for (int rr = 0; rr < RPW; ++rr) {
        float4 xs = ((const float4*)sx[w][rr])[q];
        float4 t1s = ((const float4*)st1[w][rr])[q];
        float4 t2s = ((const float4*)st2[w][rr])[q];
        acc[rr] += w0.x * xs.x + w0.y * xs.y + w0.z * xs.z + w0.w * xs.w;
        acc[rr] += w1.x * t1s.x + w1.y * t1s.y + w1.z * t1s.z + w1.w * t1s.w;
        acc[rr] += w2.x * t2s.x + w2.y * t2s.y + w2.z * t2s.z + w2.w * t2s.w;
      }
    }
    __syncthreads();
  }

  if constexpr (SMAX) {
    float bb = (o < Cout) ? B[o] : 0.f;
#pragma unroll
    for (int rr = 0; rr < RPW; ++rr) {
      int i = r0 + rr;
      if (i < n) {
        float v = (o < Cout) ? (acc[rr] + bb) : -1e30f;
        float m = v;
        for (int s = 32; s > 0; s >>= 1) m = fmaxf(m, __shfl_xor(m, s));
        float e = (o < Cout) ? __expf(v - m) : 0.f;
        float sum = e;
        for (int s = 32; s > 0; s >>= 1) sum += __shfl_xor(sum, s);
        if (o < Cout) OUT[(long)i * Cout + o] = e / sum;
      }
    }
  } else {
    if (o < Cout) {
      float bb = B[oc];
#pragma unroll
      for (int rr = 0; rr < RPW; ++rr) {
        int i = r0 + rr;
        if (i < n) {
          float v = fmaxf(acc[rr] + bb, 0.f);
          long off = (long)i * Cout + o;
          OUT[off] = v;
          OUTh[off] = __float2bfloat16(v);
        }
      }
    }
  }
}

// ---------------- mid-layer combine: [X|t1|t2] @ Wp + b (+relu), t2 gathered ----------------
template <int ROWS, int CW>
__global__ __launch_bounds__(256) void k_combine(
    VSrc src, const float* __restrict__ T1, const bf16* __restrict__ T1h,
    const float4* __restrict__ Wp, const float* __restrict__ B,
    const int* __restrict__ cnt, const int2* __restrict__ ell,
    int nbase, int n, int Cin, int Cout,
    float* __restrict__ OUT, bf16* __restrict__ OUTh) {
  constexpr int RW = 4 / CW;
  constexpr int RPW = (ROWS * CW) / 4;
  static_assert(RPW * RW == ROWS, "bad ROWS/CW combo");

  __shared__ __align__(16) float sx[4][RPW][64];
  __shared__ __align__(16) float st1[4][RPW][64];
  __shared__ __align__(16) float st2[4][RPW][64];

  int tid = threadIdx.x;
  int w = tid >> 6;
  int lane = tid & 63;
  int rg = w / CW;
  int cw = w % CW;

  int colTiles = (Cout + 63) >> 6;
  int ct = blockIdx.x % colTiles;
  int rt = blockIdx.x / colTiles;
  int r0 = rt * ROWS + rg * RPW;
  int o = ct * 64 + lane;
  int oc = (o < Cout) ? o : (Cout - 1);
  int nch = (Cin + 63) >> 6;
  int KQ = Cin >> 2;

  float acc[RPW];
#pragma unroll
  for (int r = 0; r < RPW; ++r) acc[r] = 0.f;

  for (int cg = 0; cg < nch; cg += CW) {
    int c = cg + cw;
    bool act = c < nch;
    int k0 = c * 64;
    int kw = act ? ((Cin - k0 < 64) ? (Cin - k0) : 64) : 0;
    int k = k0 + lane;
    bool kv = act && (lane < kw);

#pragma unroll
    for (int rr = 0; rr < RPW; ++rr) {
      int i = r0 + rr;
      bool iv = i < n;
      float xv = 0.f, tv = 0.f, t2v = 0.f;
      if (kv && iv) {
        xv = vloadf(src, i, k);
        tv = T1[(long)i * Cin + k];
        int g = nbase + i;
        int d = cnt[g]; if (d > MAXD) d = MAXD;
        const int2* cols = ell + (long)g * MAXD;
        float a2 = 0.f;
        for (int t = 0; t < d; t += 8) {
          int ci[8]; float wj[8];
#pragma unroll
          for (int j = 0; j < 8; ++j) {
            int tt = t + j;
            int2 e = cols[(tt < d) ? tt : 0];
            ci[j] = e.x;
            wj[j] = (tt < d) ? __int_as_float(e.y) : 0.f;
          }
#pragma unroll
          for (int j = 0; j < 8; ++j)
            a2 += wj[j] * bf2f(T1h[(long)ci[j] * Cin + k]);
        }
        t2v = 2.f * a2 - xv;
      }
      sx[w][rr][lane] = xv;
      st1[w][rr][lane] = tv;
      st2[w][rr][lane] = t2v;
    }
    __syncthreads();

    int kw4 = kw >> 2;
    int kqb = k0 >> 2;
    int qb = 0;
    // 8-deep W preload (mid W is L2-cold)
    for (; qb + 8 <= kw4; qb += 8) {
      float4 wb0[8], wb1[8], wb2[8];
#pragma unroll
      for (int q = 0; q < 8; ++q) {
        int kq = kqb + qb + q;
        wb0[q] = Wp[(0 * KQ + kq) * Cout + oc];
        wb1[q] = Wp[(1 * KQ + kq) * Cout + oc];
        wb2[q] = Wp[(2 * KQ + kq) * Cout + oc];
      }
#pragma unroll
      for (int q = 0; q < 8; ++q) {
#pragma unroll
        for (int rr = 0; rr < RPW; ++rr) {
          float4 xs = ((const float4*)sx[w][rr])[qb + q];
          float4 t1s = ((const float4*)st1[w][rr])[qb + q];
          float4 t2s = ((const float4*)st2[w][rr])[qb + q];
          acc[rr] += wb0[q].x * xs.x + wb0[q].y * xs.y + wb0[q].z * xs.z + wb0[q].w * xs.w;
          acc[rr] += wb1[q].x * t1s.x + wb1[q].y * t1s.y + wb1[q].z * t1s.z + wb1[q].w * t1s.w;
          acc[rr] += wb2[q].x * t2s.x + wb2[q].y * t2s.y + wb2[q].z * t2s.z + wb2[q].w * t2s.w;
        }
      }
    }
    for (int q = qb; q < kw4; ++q) {
      int kq = kqb + q;
      float4 w0 = Wp[(0 * KQ + kq) * Cout + oc];
      float4 w1 = Wp[(1 * KQ + kq) * Cout + oc];
      float4 w2 = Wp[(2 * KQ + kq) * Cout + oc];
#pragma unroll
      for (int rr = 0; rr < RPW; ++rr) {
        float4 xs = ((const float4*)sx[w][rr])[q];
        float4 t1s = ((const float4*)st1[w][rr])[q];
        float4 t2s = ((const float4*)st2[w][rr])[q];
        acc[rr] += w0.x * xs.x + w0.y * xs.y + w0.z * xs.z + w0.w * xs.w;
        acc[rr] += w1.x * t1s.x + w1.y * t1s.y + w1.z * t1s.z + w1.w * t1s.w;
        acc[rr] += w2.x * t2s.x + w2.y * t2s.y + w2.z * t2s.z + w2.w * t2s.w;
      }
    }
    __syncthreads();
  }

  if constexpr (CW == 1) {
    if (o < Cout) {
      float bb = B[oc];
#pragma unroll
      for (int rr = 0; rr < RPW; ++rr) {
        int i = r0 + rr;
        if (i < n) {
          float v = fmaxf(acc[rr] + bb, 0.f);
          long off = (long)i * Cout + o;
          OUT[off] = v;
          OUTh[off] = __float2bfloat16(v);
        }
      }
    }
  } else {
#pragma unroll
    for (int rr = 0; rr < RPW; ++rr) sx[w][rr][lane] = acc[rr];
    __syncthreads();
    if (cw == 0 && o < Cout) {
      float bb = B[oc];
#pragma unroll
      for (int rr = 0; rr < RPW; ++rr) {
        int i = r0 + rr;
        if (i < n) {
          float v = bb;
#pragma unroll
          for (int j = 0; j < CW; ++j) v += sx[rg * CW + j][rr][lane];
          v = fmaxf(v, 0.f);
          long off = (long)i * Cout + o;
          OUT[off] = v;
          OUTh[off] = __float2bfloat16(v);
        }
      }
    }
  }
}

// ---------------- launcher ----------------
extern "C" void kernel_launch(void* const* d_in, const int* in_sizes, int n_in,
                              void* d_out, int out_size, void* d_ws, size_t ws_size,
                              hipStream_t stream) {
  static const int NV[6] = {42, 162, 642, 2562, 10242, 40962};
  static const int NE[6] = {240, 960, 3840, 15360, 61440, 245760};
  const int NT = 54612;
  const int ET = 327600;

  EdgeParams ep;
  {
    int nb = 0, eb = 0;
    for (int l = 0; l < 6; ++l) {
      ep.e[l] = (const int*)d_in[1 + l];
      ep.E[l] = NE[l];
      ep.ebase[l] = eb;
      ep.nbase[l] = nb;
      eb += NE[l];
      nb += NV[l];
    }
  }
  const float* x0f = (const float*)d_in[0];
  const int* up[5];
  for (int i = 0; i < 5; ++i) up[i] = (const int*)d_in[7 + i];  // up2..up6
  const float *W[11], *Bb[11];
  for (int i = 0; i < 11; ++i) {
    W[i] = (const float*)d_in[12 + 2 * i];
    Bb[i] = (const float*)d_in[13 + 2 * i];
  }
  static const int LCI[11] = {4, 32, 64, 128, 256, 512, 768, 384, 192, 96, 36};
  static const int LCO[11] = {32, 64, 128, 256, 512, 512, 256, 128, 64, 32, 37};

  // ---- workspace carve (16B-aligned) ----
  char* p = (char*)d_ws;
  auto alloc_b = [&](size_t bytes) { void* r = (void*)p; p += (bytes + 15) & ~size_t(15); return r; };
  auto alloc_i = [&](size_t ne) { return (int*)alloc_b(ne * 4); };
  auto alloc_f = [&](size_t ne) { return (float*)alloc_b(ne * 4); };
  auto alloc_h = [&](size_t ne) { return (bf16*)alloc_b(ne * 2); };
  int* cnt = alloc_i(NT);
  int2* ell = (int2*)alloc_b((size_t)NT * MAXD * 8);
  float* t1f = alloc_f((size_t)40962 * 36);   // mid-layer fp32 t1
  bf16* t1h = alloc_h((size_t)40962 * 36);
  bf16* t2h = alloc_h((size_t)40962 * 36);
  bf16* x0h = alloc_h((size_t)40962 * 4);
  bf16* xh = alloc_h((size_t)40962 * 36);     // L10/L11 materialized bf16 X
  float* wp[11];
  for (int i = 0; i < 11; ++i) wp[i] = alloc_f((size_t)3 * LCI[i] * LCO[i]);
  float *af[10]; bf16 *ah[10];
  const int an[10] = {40962, 10242, 2562, 642, 162, 42, 162, 642, 2562, 10242};
  const int ac[10] = {32, 64, 128, 256, 512, 512, 256, 128, 64, 32};
  for (int i = 0; i < 10; ++i) {
    af[i] = alloc_f((size_t)an[i] * ac[i]);
    ah[i] = alloc_h((size_t)an[i] * ac[i]);
  }

  hipMemsetAsync(cnt, 0, (size_t)NT * 4, stream);
  k_fill<<<(ET + 255) / 256, 256, 0, stream>>>(ep, cnt, ell, ET);
  k_wfill<<<(NT * MAXD + 255) / 256, 256, 0, stream>>>(ep, cnt, ell, NT);
  {
    WPack P;
    int TOT = 0;
    for (int i = 0; i < 11; ++i) {
      P.src[i] = W[i];
      P.dst[i] = wp[i];
      P.cin[i] = LCI[i];
      P.cout[i] = LCO[i];
      P.tot[i] = 3 * LCI[i] * LCO[i];
      TOT += P.tot[i];
    }
    P.x0 = x0f; P.x0h = x0h; P.nx0 = 40962 * 4;
    k_wpack<<<(TOT + P.nx0 + 255) / 256, 256, 0, stream>>>(P, TOT);
  }

  auto plain = [](const float* hf, const bf16* hh, int Ch) {
    VSrc s{hf, hh, nullptr, nullptr, nullptr, 0, Ch, 0}; return s;
  };
  auto upsrc = [](const float* hf, const bf16* hh, const float* skf, const bf16* skh,
                  const int* u, int nprev, int Ch, int Cs) {
    VSrc s{hf, hh, skf, skh, u, nprev, Ch, Cs}; return s;
  };

  // big layer: bf16-only pipeline (prop_flat -> prop2 -> combine_big)
  auto big = [&](const bf16* Xh, float* OUT, bf16* OUTh, int lvl, int n,
                 int Cin, int Cout, const float* Wq, const float* Bp, int smax) {
    int nb = ep.nbase[lvl];
    int t4p = (n >> 1) * (Cin >> 2);
    k_prop_flat<<<(t4p + 255) / 256, 256, 0, stream>>>(Xh, t1h, cnt, ell, nb, n, Cin);
    k_prop2<<<(t4p + 255) / 256, 256, 0, stream>>>(Xh, t1h, t2h, cnt, ell, nb, n, Cin);
    int grid = ((Cout + 63) / 64) * ((n + 7) / 8);
    if (smax)
      k_combine_big<1><<<grid, 256, 0, stream>>>(Xh, t1h, t2h, (const float4*)Wq, Bp, n, Cin, Cout, OUT, OUTh);
    else
      k_combine_big<0><<<grid, 256, 0, stream>>>(Xh, t1h, t2h, (const float4*)Wq, Bp, n, Cin, Cout, OUT, OUTh);
  };

  // mid layer: virtual prop + gather-combine with W batching
#define MID(RS, CWv, s, OUT, OUTh, lvl, n, Cin, Cout, Wq, Bp)                                   \
  {                                                                                             \
    int nb = ep.nbase[lvl];                                                                     \
    int t2n = (n) * ((Cin) >> 1);                                                               \
    k_prop_v<<<(t2n + 255) / 256, 256, 0, stream>>>(s, t1f, t1h, cnt, ell, nb, n, Cin);         \
    int grid = (((Cout) + 63) / 64) * (((n) + (RS)-1) / (RS));                                  \
    k_combine<RS, CWv><<<grid, 256, 0, stream>>>(s, t1f, t1h, (const float4*)Wq,                \
                                                 Bp, cnt, ell, nb, n, Cin, Cout, OUT, OUTh);    \
  }

  // ---- L1: n=40962, 4->32 ----
  big(x0h, af[0], ah[0], 5, 40962, 4, 32, wp[0], Bb[0], 0);
  // ---- L2: n=10242, 32->64 ----
  big(ah[0], af[1], ah[1], 4, 10242, 32, 64, wp[1], Bb[1], 0);
  // ---- mid encoder ----
  MID(4, 1, plain(af[1], ah[1], 64), af[2], ah[2], 3, 2562, 64, 128, wp[2], Bb[2]);
  MID(2, 2, plain(af[2], ah[2], 128), af[3], ah[3], 2, 642, 128, 256, wp[3], Bb[3]);
  MID(1, 4, plain(af[3], ah[3], 256), af[4], ah[4], 1, 162, 256, 512, wp[4], Bb[4]);
  MID(1, 4, plain(af[4], ah[4], 512), af[5], ah[5], 0, 42, 512, 512, wp[5], Bb[5]);
  // ---- mid decoder ----
  MID(1, 4, upsrc(af[5], ah[5], af[3], ah[3], up[0], 42, 512, 256), af[6], ah[6], 1, 162, 768, 256, wp[6], Bb[6]);
  MID(2, 4, upsrc(af[6], ah[6], af[2], ah[2], up[1], 162, 256, 128), af[7], ah[7], 2, 642, 384, 128, wp[7], Bb[7]);
  MID(2, 4, upsrc(af[7], ah[7], af[1], ah[1], up[2], 642, 128, 64), af[8], ah[8], 3, 2562, 192, 64, wp[8], Bb[8]);
  // ---- L10: n=10242, [64|32]->32 ----
  {
    VSrc s = upsrc(af[8], ah[8], af[0], ah[0], up[3], 2562, 64, 32);
    k_xmat<<<(10242 * 48 + 255) / 256, 256, 0, stream>>>(s, xh, 10242, 96);
    big(xh, af[9], ah[9], 4, 10242, 96, 32, wp[9], Bb[9], 0);
  }
  // ---- L11: n=40962, [32|4]->37 + softmax ----
  {
    VSrc s = upsrc(af[9], ah[9], x0f, x0h, up[4], 10242, 32, 4);
    k_xmat<<<(40962 * 18 + 255) / 256, 256, 0, stream>>>(s, xh, 40962, 36);
    big(xh, (float*)d_out, nullptr, 5, 40962, 36, 37, wp[10], Bb[10], 1);
  }
}